// Round 8
// baseline (319.647 us; speedup 1.0000x reference)
//
#include <hip/hip_runtime.h>
#include <stdint.h>

typedef unsigned short u16;
typedef float f32x4 __attribute__((ext_vector_type(4)));
typedef __bf16 bf16x8 __attribute__((ext_vector_type(8)));
typedef u16 u16x8 __attribute__((ext_vector_type(8)));
typedef u16 u16x4 __attribute__((ext_vector_type(4)));

#define SCALE_QK 0.35355339059327373f

#define BAR() asm volatile("s_barrier" ::: "memory")
#define WAIT_LGKM0() do { asm volatile("s_waitcnt lgkmcnt(0)" ::: "memory"); __builtin_amdgcn_sched_barrier(0); } while (0)
#define WAIT_VM(n) do { asm volatile("s_waitcnt vmcnt(" #n ")" ::: "memory"); __builtin_amdgcn_sched_barrier(0); } while (0)

__device__ __forceinline__ u16 f2bf(float f) {
  union { float f; uint32_t u; } x; x.f = f;
  uint32_t r = x.u + 0x7fffu + ((x.u >> 16) & 1u);
  return (u16)(r >> 16);
}
__device__ __forceinline__ float bf2f(u16 h) {
  union { uint32_t u; float f; } x; x.u = ((uint32_t)h) << 16;
  return x.f;
}
__device__ __forceinline__ void gload16(const void* g, void* l) {
  __builtin_amdgcn_global_load_lds((const __attribute__((address_space(1))) void*)g,
                                   (__attribute__((address_space(3))) void*)l, 16, 0, 0);
}
__device__ __forceinline__ bf16x8 ld_f32_to_bf8(const float* p) {
  f32x4 a = *(const f32x4*)p, b = *(const f32x4*)(p + 4);
  union { u16x8 u; bf16x8 h; } c;
  c.u[0] = f2bf(a[0]); c.u[1] = f2bf(a[1]); c.u[2] = f2bf(a[2]); c.u[3] = f2bf(a[3]);
  c.u[4] = f2bf(b[0]); c.u[5] = f2bf(b[1]); c.u[6] = f2bf(b[2]); c.u[7] = f2bf(b[3]);
  return c.h;
}

// ---------------- merged prep: hidden->bf16 (blocks 0..8191) + weight transpose (blocks 8192..8959) ----------------
__global__ __launch_bounds__(256) void k_prep(const float* __restrict__ hidden,
                                              const float* __restrict__ Wq, const float* __restrict__ Wk,
                                              const float* __restrict__ Wv,
                                              u16* __restrict__ hb, u16* __restrict__ Wt) {
  __shared__ float tile[64][65];
  const int bx = blockIdx.x;
  const int t = threadIdx.x;
  if (bx < 8192) {
    const size_t i = ((size_t)bx * 256 + t) * 8;
    f32x4 v0 = *(const f32x4*)(hidden + i);
    f32x4 v1 = *(const f32x4*)(hidden + i + 4);
    u16x8 o;
    o[0] = f2bf(v0[0]); o[1] = f2bf(v0[1]); o[2] = f2bf(v0[2]); o[3] = f2bf(v0[3]);
    o[4] = f2bf(v1[0]); o[5] = f2bf(v1[1]); o[6] = f2bf(v1[2]); o[7] = f2bf(v1[3]);
    *(u16x8*)(hb + i) = o;
    return;
  }
  const int bxx = bx - 8192;
  const int w = bxx >> 8, tn = (bxx >> 4) & 15, tk = bxx & 15;
  const float* W = (w == 0) ? Wq : ((w == 1) ? Wk : Wv);
  const int r = t >> 2, c0 = (t & 3) * 16;
  const float* src = W + (size_t)(tk * 64 + r) * 1024 + tn * 64 + c0;
#pragma unroll
  for (int j = 0; j < 16; j += 4) {
    f32x4 x = *(const f32x4*)(src + j);
    tile[r][c0 + j + 0] = x[0]; tile[r][c0 + j + 1] = x[1];
    tile[r][c0 + j + 2] = x[2]; tile[r][c0 + j + 3] = x[3];
  }
  __syncthreads();
  u16* dst = Wt + (size_t)(w * 1024 + tn * 64 + r) * 1024 + tk * 64 + c0;
#pragma unroll
  for (int j = 0; j < 16; ++j) dst[j] = f2bf(tile[c0 + j][r]);
}

// ---------------- 256x256x64 8-wave GEMM, counted-vmcnt pipeline + XCD-aware swizzle ----------------
__device__ __forceinline__ bf16x8 frg(const u16* buf, int row, int ks, int lhi) {
  const int ck = (ks << 2) + lhi;
  return *reinterpret_cast<const bf16x8*>(buf + (row << 6) + ((ck ^ (row & 7)) << 3));
}
__device__ __forceinline__ void issue(const u16* g, int rowbase, int tc, u16* ldsbase, int wid) {
  gload16(g + (((size_t)rowbase) << 10) + tc, ldsbase + ((rowbase + (wid << 3)) << 6));
}
template <int Q>
__device__ __forceinline__ void quad_mfma(const bf16x8 (&af)[2][2], const bf16x8 (&bf)[4][2],
                                          f32x4 (&acc)[8][4]) {
#pragma unroll
  for (int mm = 0; mm < 2; ++mm)
#pragma unroll
    for (int n = 0; n < 4; ++n) {
      acc[Q * 2 + mm][n] = __builtin_amdgcn_mfma_f32_16x16x32_bf16(af[mm][0], bf[n][0], acc[Q * 2 + mm][n], 0, 0, 0);
      acc[Q * 2 + mm][n] = __builtin_amdgcn_mfma_f32_16x16x32_bf16(af[mm][1], bf[n][1], acc[Q * 2 + mm][n], 0, 0, 0);
    }
}
#define LOADA_TO(dst, Q)                                     \
  dst[0][0] = frg(ASr, rA0 + (Q)*32, 0, lhi);                \
  dst[0][1] = frg(ASr, rA0 + (Q)*32, 1, lhi);                \
  dst[1][0] = frg(ASr, rA0 + (Q)*32 + 16, 0, lhi);           \
  dst[1][1] = frg(ASr, rA0 + (Q)*32 + 16, 1, lhi);

__global__ __launch_bounds__(512) void k_gemm2(const u16* __restrict__ A, const u16* __restrict__ Bt,
                                               const float* __restrict__ bq, const float* __restrict__ bk,
                                               const float* __restrict__ bv,
                                               u16* __restrict__ oq, u16* __restrict__ ok, u16* __restrict__ ov,
                                               float* __restrict__ ql, float* __restrict__ kl) {
  __shared__ __align__(16) u16 AS[2][256 * 64];
  __shared__ __align__(16) u16 BS[2][256 * 64];
  __shared__ __align__(16) u16 obuf[8][16][70];
  const int t = threadIdx.x, lane = t & 63, wid = t >> 6;
  const int wm = wid >> 2, wn = wid & 3;
  // XCD-aware swizzle (T1): xcd = id&7 owns bm range [8*xcd, 8*xcd+8), bn varies fastest
  // -> A-tile (0.5MB) reused 12x from the XCD's private L2 instead of L3.
  const int bi = blockIdx.x;
  const int bm = ((bi & 7) << 3) + (bi >> 3) / 12;
  const int bn = (bi >> 3) % 12;
  const int l15 = lane & 15, lhi = lane >> 4;

  const int rowoff = t >> 3;
  const int cswz = (t & 7) ^ (rowoff & 7);
  const u16* aG = A + (((size_t)(bm * 256 + rowoff)) << 10) + (cswz << 3);
  const u16* bG = Bt + (((size_t)(bn * 256 + rowoff)) << 10) + (cswz << 3);

  const int rA0 = wm * 128 + l15;
  const int rB0 = wn * 64 + l15;

  f32x4 acc[8][4];
#pragma unroll
  for (int m = 0; m < 8; ++m)
#pragma unroll
    for (int n = 0; n < 4; ++n) acc[m][n] = (f32x4){0.f, 0.f, 0.f, 0.f};

  // prologue: tile 0 -> buf 0. Order: B x4, A-q01 x2, A-q23 x2.
  issue(bG, 0, 0, BS[0], wid);
  issue(bG, 64, 0, BS[0], wid);
  issue(bG, 128, 0, BS[0], wid);
  issue(bG, 192, 0, BS[0], wid);
  issue(aG, 0, 0, AS[0], wid);
  issue(aG, 128, 0, AS[0], wid);
  issue(aG, 64, 0, AS[0], wid);
  issue(aG, 192, 0, AS[0], wid);
  WAIT_VM(2);  // B + A-q01 landed; A-q23 in flight
  BAR();

  for (int u = 0; u < 15; ++u) {
    const int pu = u & 1;
    const u16* ASr = AS[pu];
    const u16* BSr = BS[pu];
    u16* ASw = AS[pu ^ 1];
    u16* BSw = BS[pu ^ 1];
    const int tc = (u + 1) << 6;
    bf16x8 bfr[4][2];
    bf16x8 afA[2][2], afB[2][2];
    // P0: read B(8) + A-q0 + A-q1; issue ALL 8 next-tile loads; MFMA q0
#pragma unroll
    for (int n = 0; n < 4; ++n) {
      bfr[n][0] = frg(BSr, rB0 + n * 16, 0, lhi);
      bfr[n][1] = frg(BSr, rB0 + n * 16, 1, lhi);
    }
    LOADA_TO(afA, 0)
    LOADA_TO(afB, 1)
    issue(bG, 0, tc, BSw, wid);
    issue(bG, 64, tc, BSw, wid);
    issue(bG, 128, tc, BSw, wid);
    issue(bG, 192, tc, BSw, wid);
    issue(aG, 0, tc, ASw, wid);
    issue(aG, 128, tc, ASw, wid);
    issue(aG, 64, tc, ASw, wid);
    issue(aG, 192, tc, ASw, wid);
    __builtin_amdgcn_s_setprio(1);
    quad_mfma<0>(afA, bfr, acc);
    __builtin_amdgcn_s_setprio(0);
    WAIT_VM(8);  // cur-tile A-q23 landed (8 next-tile loads remain in flight)
    BAR();
    // P1: read A-q2; MFMA q1
    LOADA_TO(afA, 2)
    __builtin_amdgcn_s_setprio(1);
    quad_mfma<1>(afB, bfr, acc);
    __builtin_amdgcn_s_setprio(0);
    // P2: read A-q3; MFMA q2
    LOADA_TO(afB, 3)
    __builtin_amdgcn_s_setprio(1);
    quad_mfma<2>(afA, bfr, acc);
    __builtin_amdgcn_s_setprio(0);
    // P3: MFMA q3
    __builtin_amdgcn_s_setprio(1);
    quad_mfma<3>(afB, bfr, acc);
    __builtin_amdgcn_s_setprio(0);
    WAIT_VM(2);  // next-tile B + A-q01 landed; A-q23 stays in flight
    BAR();       // tile boundary
  }
  // peeled tile 15 (buf 1; 2 loads of its A-q23 still in flight at entry)
  {
    const u16* ASr = AS[1];
    const u16* BSr = BS[1];
    bf16x8 bfr[4][2];
    bf16x8 afA[2][2], afB[2][2];
#pragma unroll
    for (int n = 0; n < 4; ++n) {
      bfr[n][0] = frg(BSr, rB0 + n * 16, 0, lhi);
      bfr[n][1] = frg(BSr, rB0 + n * 16, 1, lhi);
    }
    LOADA_TO(afA, 0)
    LOADA_TO(afB, 1)
    quad_mfma<0>(afA, bfr, acc);
    WAIT_VM(0);
    BAR();
    LOADA_TO(afA, 2)
    quad_mfma<1>(afB, bfr, acc);
    LOADA_TO(afB, 3)
    quad_mfma<2>(afA, bfr, acc);
    quad_mfma<3>(afB, bfr, acc);
  }

  // ---- epilogue: bias+scale, LDS bounce, coalesced stores; fused landmark means ----
  const int which = bn >> 2;
  const float* bias = (which == 0) ? bq : ((which == 1) ? bk : bv);
  u16* op = (which == 0) ? oq : ((which == 1) ? ok : ov);
  const float scl = (which < 2) ? SCALE_QK : 1.0f;
  const int h = ((bn & 3) << 2) + wn;  // wave's single head
  const int rowBase2 = (bm << 8) + (wm << 7);
  const int rl = lhi << 2;
  const int srow = lane >> 2, d0 = (lane & 3) * 16;
  float bb[4];
#pragma unroll
  for (int n = 0; n < 4; ++n) bb[n] = bias[((bn & 3) << 8) + (wn << 6) + n * 16 + l15];
#pragma unroll
  for (int m = 0; m < 8; ++m) {
#pragma unroll
    for (int n = 0; n < 4; ++n)
#pragma unroll
      for (int r = 0; r < 4; ++r)
        obuf[wid][rl + r][n * 16 + l15] = f2bf((acc[m][n][r] + bb[n]) * scl);
    const int gm = rowBase2 + m * 16 + srow;
    const int b_ = gm >> 12, s = gm & 4095;
    u16* dst = op + (((size_t)b_ * 16 + h) * 4096 + s) * 64 + d0;
    *(u16x8*)dst = *(const u16x8*)&obuf[wid][srow][d0];
    *(u16x8*)(dst + 8) = *(const u16x8*)&obuf[wid][srow][d0 + 8];
  }
  // landmark segment means (q/k only)
  if (which < 2) {
    float* lmp = (which == 0) ? ql : kl;
    const int bh = ((bm >> 4) << 4) + h;
#pragma unroll
    for (int sg = 0; sg < 2; ++sg) {
#pragma unroll
      for (int n = 0; n < 4; ++n) {
        float s = 0.f;
#pragma unroll
        for (int mi = 0; mi < 4; ++mi)
#pragma unroll
          for (int r = 0; r < 4; ++r) s += (acc[sg * 4 + mi][n][r] + bb[n]) * scl;
        s += __shfl_xor(s, 16, 64);
        s += __shfl_xor(s, 32, 64);
        if (lhi == 0) {
          const int lseg = ((bm & 15) << 2) + (wm << 1) + sg;
          lmp[(size_t)bh * 4096 + lseg * 64 + n * 16 + l15] = s * 0.015625f;
        }
      }
    }
  }
}

// ---------------- kernel_2 = softmax(ql@kl^T); k2t + colmax; also emit klb bf16 ----------------
__global__ __launch_bounds__(256) void k_k2(const float* __restrict__ ql, const float* __restrict__ kl,
                                            float* __restrict__ k2t, float* __restrict__ colmax,
                                            u16* __restrict__ klb) {
  __shared__ __align__(16) float qlT[64 * 68];
  __shared__ __align__(16) float klT[64 * 68];
  __shared__ __align__(16) float sc[64 * 68];
  const int bh = blockIdx.x, t = threadIdx.x;
  {
    const int r = t >> 2, c0 = (t & 3) * 16;
    const float* qp = ql + (size_t)bh * 4096 + r * 64 + c0;
    const float* kp = kl + (size_t)bh * 4096 + r * 64 + c0;
    u16* kb_ = klb + (size_t)bh * 4096 + r * 64 + c0;
#pragma unroll
    for (int j = 0; j < 16; ++j) {
      qlT[(c0 + j) * 68 + r] = qp[j];
      const float kv = kp[j];
      klT[(c0 + j) * 68 + r] = kv;
      kb_[j] = f2bf(kv);
    }
  }
  __syncthreads();
  {
    const int mg = (t >> 4) * 4, lg = (t & 15) * 4;
    float acc[4][4];
#pragma unroll
    for (int i = 0; i < 4; ++i)
#pragma unroll
      for (int j = 0; j < 4; ++j) acc[i][j] = 0.f;
    for (int d0 = 0; d0 < 64; ++d0) {
      f32x4 x = *(const f32x4*)&qlT[d0 * 68 + mg];
      f32x4 y = *(const f32x4*)&klT[d0 * 68 + lg];
#pragma unroll
      for (int i = 0; i < 4; ++i)
#pragma unroll
        for (int j = 0; j < 4; ++j) acc[i][j] += x[i] * y[j];
    }
#pragma unroll
    for (int i = 0; i < 4; ++i)
#pragma unroll
      for (int j = 0; j < 4; ++j) sc[(mg + i) * 68 + lg + j] = acc[i][j];
  }
  __syncthreads();
  if (t < 64) {
    float mx = -1e30f;
    for (int l = 0; l < 64; ++l) mx = fmaxf(mx, sc[t * 68 + l]);
    float sum = 0.f;
    for (int l = 0; l < 64; ++l) { float e = __expf(sc[t * 68 + l] - mx); sc[t * 68 + l] = e; sum += e; }
    const float inv = 1.0f / sum;
    for (int l = 0; l < 64; ++l) sc[t * 68 + l] *= inv;
  }
  __syncthreads();
  {
    const int r = t >> 2, c0 = (t & 3) * 16;
    float* ot = k2t + (size_t)bh * 4096 + r * 64 + c0;
#pragma unroll
    for (int j = 0; j < 16; ++j) ot[j] = sc[(c0 + j) * 68 + r];
  }
  if (t < 64) {
    float s = 0.f;
    for (int m = 0; m < 64; ++m) s += sc[m * 68 + t];
    for (int off = 32; off; off >>= 1) s = fmaxf(s, __shfl_down(s, off, 64));
    if (t == 0) colmax[bh] = s;
  }
}

// ---------------- merged mid: blocks 0..63 = pinv (XOR-swizzled LDS), 64..575 = s3+nv ----------------
__device__ __forceinline__ int pidx(int row, int c) {
  return (row << 6) + ((((c >> 2) ^ (row & 15)) << 2) | (c & 3));
}
__device__ __forceinline__ void mm64s(const float* __restrict__ X, const float* __restrict__ Y,
                                      int row, int c0, float* __restrict__ acc) {
#pragma unroll
  for (int j = 0; j < 8; ++j) acc[j] = 0.f;
  for (int kc = 0; kc < 16; ++kc) {
    f32x4 xq = *(const f32x4*)&X[pidx(row, kc << 2)];
#pragma unroll
    for (int kk = 0; kk < 4; ++kk) {
      const int k = (kc << 2) + kk;
      f32x4 y0 = *(const f32x4*)&Y[pidx(k, c0)];
      f32x4 y1 = *(const f32x4*)&Y[pidx(k, c0 + 4)];
      const float x = xq[kk];
#pragma unroll
      for (int j = 0; j < 4; ++j) { acc[j] += x * y0[j]; acc[4 + j] += x * y1[j]; }
    }
  }
}

__global__ __launch_bounds__(512) void k_mid(const float* __restrict__ k2t, const float* __restrict__ colmax,
                                             float* __restrict__ pinv,
                                             const float* __restrict__ ql, const u16* __restrict__ kb,
                                             const u16* __restrict__ vb,
                                             float* __restrict__ nvp, float* __restrict__ zp) {
  __shared__ __align__(16) char smem_s[81920];
  __shared__ float gsh;
  const int t = threadIdx.x;
  if (blockIdx.x < 64) {
    // ======== pinv: 6 Newton-Schulz iterations, all LDS XOR-swizzled [64][64] f32 ========
    float* aS = (float*)smem_s;        // a (normal layout)
    float* vl = aS + 4096;             // val
    float* kv = vl + 4096;
    float* t1 = kv + 4096;
    float* t2 = t1 + 4096;
    const int bh = blockIdx.x;
    const float* aT = k2t + (size_t)bh * 4096;  // aT[k][r] = a[r][k]
    if (t < 64) {
      float v = colmax[t];
      for (int off = 32; off; off >>= 1) v = fmaxf(v, __shfl_down(v, off, 64));
      if (t == 0) gsh = v;
    }
    const int row = t >> 3, c0 = (t & 7) << 3;
    // stage a into LDS: aS[r][k] = aT[k*64+r]
#pragma unroll
    for (int j = 0; j < 8; ++j) {
      const int i = t * 8 + j;
      aS[pidx(i & 63, i >> 6)] = aT[i];
    }
    __syncthreads();
    const float ginv = 1.0f / gsh;
    {
      f32x4 v0 = *(const f32x4*)(aT + row * 64 + c0);
      f32x4 v1 = *(const f32x4*)(aT + row * 64 + c0 + 4);
      v0 *= ginv; v1 *= ginv;
      *(f32x4*)&vl[pidx(row, c0)] = v0;       // val0[r][c] = aT[r][c]/g
      *(f32x4*)&vl[pidx(row, c0 + 4)] = v1;
    }
    __syncthreads();
    float acc[8];
    for (int it = 0; it < 6; ++it) {
      mm64s(aS, vl, row, c0, acc);            // kv = a @ val
#pragma unroll
      for (int j = 0; j < 8; ++j) kv[pidx(row, c0 + j)] = acc[j];
      __syncthreads();
#pragma unroll
      for (int j = 0; j < 8; ++j) {           // t1 = 7I - kv
        const int c = c0 + j;
        t1[pidx(row, c)] = ((row == c) ? 7.0f : 0.0f) - kv[pidx(row, c)];
      }
      __syncthreads();
      mm64s(kv, t1, row, c0, acc);            // t2 = 15I - kv@t1
#pragma unroll
      for (int j = 0; j < 8; ++j) {
        const int c = c0 + j;
        t2[pidx(row, c)] = ((row == c) ? 15.0f : 0.0f) - acc[j];
      }
      __syncthreads();
      mm64s(kv, t2, row, c0, acc);            // t1 = 13I - kv@t2
#pragma unroll
      for (int j = 0; j < 8; ++j) {
        const int c = c0 + j;
        t1[pidx(row, c)] = ((row == c) ? 13.0f : 0.0f) - acc[j];
      }
      __syncthreads();
      mm64s(vl, t1, row, c0, acc);            // t2 = 0.25 * val@t1
#pragma unroll
      for (int j = 0; j < 8; ++j) t2[pidx(row, c0 + j)] = 0.25f * acc[j];
      __syncthreads();
#pragma unroll
      for (int j = 0; j < 8; ++j) vl[pidx(row, c0 + j)] = t2[pidx(row, c0 + j)];  // val = t2
      __syncthreads();
    }
    {
      f32x4 o0 = *(const f32x4*)&vl[pidx(row, c0)];
      f32x4 o1 = *(const f32x4*)&vl[pidx(row, c0 + 4)];
      *(f32x4*)(pinv + (size_t)bh * 4096 + row * 64 + c0) = o0;
      *(f32x4*)(pinv + (size_t)bh * 4096 + row * 64 + c0 + 4) = o1;
    }
    return;
  }
  // ======== s3+nv: 512 threads = 2 S-halves x 4 L-quarter waves ========
  u16* VTs = (u16*)smem_s;                    // [2 buf][2 half][64][72]
  u16* els = (u16*)(smem_s + 36864);          // [8][16][72]
  const int id = (int)blockIdx.x - 64;
  const int bh = id & 63, scn = id >> 6;      // scn in [0,8)
  const int lane = t & 63, w = t >> 6;
  const int wq = w & 3, half = w >> 2;
  const int l15 = lane & 15, kg = (lane >> 4) << 3, rl = (lane >> 4) << 2;
  const float* aRow = ql + (size_t)bh * 4096 + (wq * 16 + l15) * 64 + kg;
  bf16x8 aql[2];
  aql[0] = ld_f32_to_bf8(aRow);
  aql[1] = ld_f32_to_bf8(aRow + 32);
  f32x4 accv[4];
#pragma unroll
  for (int n = 0; n < 4; ++n) accv[n] = (f32x4){0.f, 0.f, 0.f, 0.f};
  float zacc[4] = {0.f, 0.f, 0.f, 0.f};
  const int sBase = scn * 512 + half * 256;
  u16* VT0 = VTs + ((size_t)(0 * 2 + half) * 64) * 72;
  u16* VT1 = VTs + ((size_t)(1 * 2 + half) * 64) * 72;
  u16* elw = els + ((size_t)w * 16) * 72;
  // preload sub 0 into VT0
  {
    const u16* vp = vb + ((size_t)bh * 4096 + sBase + lane) * 64 + wq * 16;
    u16x8 h0 = *(const u16x8*)vp, h1 = *(const u16x8*)(vp + 8);
#pragma unroll
    for (int j = 0; j < 8; ++j) {
      VT0[(wq * 16 + j) * 72 + lane] = h0[j];
      VT0[(wq * 16 + 8 + j) * 72 + lane] = h1[j];
    }
  }
  __syncthreads();
  for (int sub = 0; sub < 4; ++sub) {
    const int s0 = sBase + sub * 64;
    u16x8 hn0 = {0, 0, 0, 0, 0, 0, 0, 0}, hn1 = {0, 0, 0, 0, 0, 0, 0, 0};
    if (sub < 3) {  // prefetch next V tile into regs
      const u16* vpn = vb + ((size_t)bh * 4096 + s0 + 64 + lane) * 64 + wq * 16;
      hn0 = *(const u16x8*)vpn; hn1 = *(const u16x8*)(vpn + 8);
    }
    const u16* bRow = kb + ((size_t)bh * 4096 + s0 + l15) * 64 + kg;
    f32x4 e[4];
#pragma unroll
    for (int n = 0; n < 4; ++n) e[n] = (f32x4){0.f, 0.f, 0.f, 0.f};
#pragma unroll
    for (int ks = 0; ks < 2; ++ks)
#pragma unroll
      for (int n = 0; n < 4; ++n) {
        bf16x8 bk_ = *reinterpret_cast<const bf16x8*>(bRow + n * 1024 + ks * 32);
        e[n] = __builtin_amdgcn_mfma_f32_16x16x32_bf16(aql[ks], bk_, e[n], 0, 0, 0);
      }
#pragma unroll
    for (int n = 0; n < 4; ++n)
#pragma unroll
      for (int r = 0; r < 4; ++r) {
        const float v = __expf(e[n][r]);
        zacc[r] += v;
        elw[(rl + r) * 72 + n * 16 + l15] = f2bf(v);
      }
    if (sub < 3) {
      u16* VTn = ((sub + 1) & 1) ? VT1 : VT0;
#pragma unroll
      for (int j = 0; j < 8; ++j) {
        VTn[(wq * 16 + j) * 72 + lane] = hn0[j];
        VTn[(wq * 16 + 8 + j) * 72 + lane] = hn1[j];
      }
    }
    WAIT_LGKM0();  // own e_lds + VT writes complete
    const u16* VTc = (sub & 1) ? VT1 : VT0;
#pragma unroll
    for (int ks = 0; ks < 2; ++ks) {
      bf16x8 af = *reinterpret_cast<const bf16x8*>(&elw[l15 * 72 + kg + ks * 32]);
#pragma unroll
      for (int n = 0; n < 4; ++n) {
        bf16x8 bf_ = *reinterpret_cast<const bf16x8*>(&VTc[(n * 16 + l15) * 72 + kg + ks * 32]);
        accv[n] = __builtin_amdgcn_mfma_f32_16x16x32_bf16(af, bf_, accv[n], 0, 0, 0);
      }
    }
    BAR();  // publish next VT buf; WAR fence on current
  }
  const int p = scn * 2 + half;
#pragma unroll
  for (int r = 0; r < 4; ++r)
#pragma unroll
    for (int n = 0; n < 4; ++n)
      nvp[(((size_t)p * 64 + bh) * 64 + wq * 16 + rl + r) * 64 + n * 16 + l15] = accv[n][r];
#pragma unroll
  for (int r = 0; r < 4; ++r) {
    float s = zacc[r];
    s += __shfl_xor(s, 1, 64); s += __shfl_xor(s, 2, 64);
    s += __shfl_xor(s, 4, 64); s += __shfl_xor(s, 8, 64);
    if (l15 == 0) zp[((size_t)p * 64 + bh) * 64 + wq * 16 + rl + r] = s;
  }
}

// ---------------- M^T (bf16) = (pinv @ (sum(nvp)/sum(zp)))^T ----------------
__global__ __launch_bounds__(256) void k_pnv(const float* __restrict__ pinv, const float* __restrict__ nvp,
                                             const float* __restrict__ zp, u16* __restrict__ Mtb) {
  __shared__ __align__(16) float XT[64 * 68];
  __shared__ __align__(16) float Y[64 * 68];
  const int bh = blockIdx.x, t = threadIdx.x;
  {
    const int r = t >> 2, c0 = (t & 3) * 16;
    const float* pp = pinv + (size_t)bh * 4096 + r * 64 + c0;
#pragma unroll
    for (int j = 0; j < 16; ++j) XT[(c0 + j) * 68 + r] = pp[j];
    float zs = 0.f;
#pragma unroll
    for (int p = 0; p < 16; ++p) zs += zp[((size_t)p * 64 + bh) * 64 + r];
    const float iz = 1.0f / zs;
#pragma unroll
    for (int j = 0; j < 16; ++j) {
      float s = 0.f;
#pragma unroll
      for (int p = 0; p < 16; ++p) s += nvp[(((size_t)p * 64 + bh) * 64 + r) * 64 + c0 + j];
      Y[r * 68 + c0 + j] = s * iz;
    }
  }
  __syncthreads();
  const int rg = (t >> 4) * 4, cg = (t & 15) * 4;
  float acc[4][4];
#pragma unroll
  for (int i = 0; i < 4; ++i)
#pragma unroll
    for (int j = 0; j < 4; ++j) acc[i][j] = 0.f;
  for (int k = 0; k < 64; ++k) {
    f32x4 x = *(const f32x4*)&XT[k * 68 + rg];
    f32x4 y = *(const f32x4*)&Y[k * 68 + cg];
#pragma unroll
    for (int i = 0; i < 4; ++i)
#pragma unroll
      for (int j = 0; j < 4; ++j) acc[i][j] += x[i] * y[j];
  }
#pragma unroll
  for (int j = 0; j < 4; ++j) {
    u16x4 o = {f2bf(acc[0][j]), f2bf(acc[1][j]), f2bf(acc[2][j]), f2bf(acc[3][j])};
    *(u16x4*)&Mtb[(size_t)bh * 4096 + (cg + j) * 64 + rg] = o;
  }
}

// ---------------- final: softmax(q·kl^T) @ M^T + depthwise conv ----------------
__global__ __launch_bounds__(256) void k_out(const u16* __restrict__ qb, const u16* __restrict__ vb,
                                             const u16* __restrict__ klb, const u16* __restrict__ Mtb,
                                             const float* __restrict__ cw, float* __restrict__ out) {
  __shared__ __align__(16) u16 P_lds[4][16][72];
  __shared__ __align__(16) u16 vtile_t[64][100];  // [d][row]
  __shared__ float wsh[33];
  const int bid = blockIdx.x;
  const int bh = bid >> 6, st = bid & 63;
  const int b = bh >> 4, h = bh & 15;
  const int t = threadIdx.x, lane = t & 63, w = t >> 6;
  const int sbase = st * 64;
  const int l15 = lane & 15, kg = (lane >> 4) << 3, rl = (lane >> 4) << 2;

  if (t < 33) wsh[t] = cw[h * 33 + t];
  for (int idx = t; idx < 96 * 8; idx += 256) {
    const int row = idx >> 3, c8 = idx & 7;
    const int sg = sbase + row - 16;
    u16x8 val = {0, 0, 0, 0, 0, 0, 0, 0};
    if (sg >= 0 && sg < 4096) val = *(const u16x8*)(vb + ((size_t)bh * 4096 + sg) * 64 + c8 * 8);
#pragma unroll
    for (int j = 0; j < 8; ++j) vtile_t[c8 * 8 + j][row] = val[j];
  }

  f32x4 c1[4];
#pragma unroll
  for (int n = 0; n < 4; ++n) c1[n] = (f32x4){0.f, 0.f, 0.f, 0.f};
  {
    const u16* aRow = qb + ((size_t)bh * 4096 + sbase + w * 16 + l15) * 64 + kg;
    const u16* kRow = klb + (size_t)bh * 4096 + l15 * 64 + kg;
#pragma unroll
    for (int ks = 0; ks < 2; ++ks) {
      bf16x8 af = *reinterpret_cast<const bf16x8*>(aRow + ks * 32);
#pragma unroll
      for (int n = 0; n < 4; ++n) {
        bf16x8 bf_ = *reinterpret_cast<const bf16x8*>(kRow + n * 1024 + ks * 32);
        c1[n] = __builtin_amdgcn_mfma_f32_16x16x32_bf16(af, bf_, c1[n], 0, 0, 0);
      }
    }
  }
  float invZ[4];
  {
    float z[4] = {0.f, 0.f, 0.f, 0.f};
#pragma unroll
    for (int n = 0; n < 4; ++n)
#pragma unroll
      for (int r = 0; r < 4; ++r) { float v = __expf(c1[n][r]); c1[n][r] = v; z[r] += v; }
#pragma unroll
    for (int r = 0; r < 4; ++r) {
      float s = z[r];
      s += __shfl_xor(s, 1, 64); s += __shfl_xor(s, 2, 64);
      s += __shfl_xor(s, 4, 64); s += __shfl_xor(s, 8, 64);
      invZ[r] = 1.0f / s;
    }
#pragma unroll
    for (int n = 0; n < 4; ++n)
#pragma unroll
      for (int r = 0; r < 4; ++r)
        P_lds[w][rl + r][n * 16 + l15] = f2bf(c1[n][r]);
  }
  __syncthreads();
  f32x4 c2[4];
#pragma unroll
  for (int n = 0; n < 4; ++n) c2[n] = (f32x4){0.f, 0.f, 0.f, 0.f};
  {
    const u16* mRow = Mtb + (size_t)bh * 4096 + l15 * 64 + kg;
#pragma unroll
    for (int ks = 0; ks < 2; ++ks) {
      bf16x8 af = *reinterpret_cast<const bf16x8*>(&P_lds[w][l15][kg + ks * 32]);
#pragma unroll
      for (int n = 0; n < 4; ++n) {
        bf16x8 bf_ = *reinterpret_cast<const bf16x8*>(mRow + n * 1024 + ks * 32);
        c2[n] = __builtin_amdgcn_mfma_f32_16x16x32_bf16(af, bf_, c2[n], 0, 0, 0);
      }
    }
  }
  const int base = w * 16 + rl;
#pragma unroll
  for (int n = 0; n < 4; ++n) {
    const int d = n * 16 + l15;
    float vcol[36];
#pragma unroll
    for (int k8 = 0; k8 < 9; ++k8) {
      u16x4 vq = *(const u16x4*)&vtile_t[d][base + k8 * 4];
      vcol[k8 * 4 + 0] = bf2f(vq[0]); vcol[k8 * 4 + 1] = bf2f(vq[1]);
      vcol[k8 * 4 + 2] = bf2f(vq[2]); vcol[k8 * 4 + 3] = bf2f(vq[3]);
    }
    float cv[4] = {0.f, 0.f, 0.f, 0.f};
#pragma unroll
    for (int jt = 0; jt < 33; ++jt) {
      const float ww = wsh[jt];
#pragma unroll
      for (int r = 0; r < 4; ++r) cv[r] += ww * vcol[r + jt];
    }
#pragma unroll
    for (int r = 0; r < 4; ++r) {
      const int sgl = sbase + base + r;
      out[((size_t)b * 4096 + sgl) * 1024 + h * 64 + d] = c2[n][r] * invZ[r] + cv[r];
    }
  }
}

extern "C" void kernel_launch(void* const* d_in, const int* in_sizes, int n_in,
                              void* d_out, int out_size, void* d_ws, size_t ws_size,
                              hipStream_t stream) {
  const float* hidden = (const float*)d_in[0];
  const float* Wq = (const float*)d_in[1];
  const float* bq = (const float*)d_in[2];
  const float* Wk = (const float*)d_in[3];
  const float* bk = (const float*)d_in[4];
  const float* Wv = (const float*)d_in[5];
  const float* bv = (const float*)d_in[6];
  const float* cw = (const float*)d_in[7];
  float* out = (float*)d_out;

  char* ws = (char*)d_ws;
  u16* qb = (u16*)(ws);                           // 32MB
  u16* kb = (u16*)(ws + 33554432ull);             // 32MB
  u16* vb = (u16*)(ws + 67108864ull);             // 32MB
  float* ql = (float*)(ws + 100663296ull);        // 1MB
  float* kl = (float*)(ws + 101711872ull);        // 1MB
  float* k2t = (float*)(ws + 102760448ull);       // 1MB
  float* pinvb = (float*)(ws + 103809024ull);     // 1MB
  u16* Mtb = (u16*)(ws + 104857600ull);           // 512KB
  u16* klb = (u16*)(ws + 105381888ull);           // 1MB
  float* stats = (float*)(ws + 106430464ull);     // 4KB
  u16* wt = (u16*)(ws + 106434560ull);            // 6MB, dead after k_gemm2
  u16* hb = (u16*)(ws + 112726016ull);            // 32MB, dead after k_gemm2
  float* nvp = (float*)(ws + 112726016ull);       // 16.8MB, aliases hb (dead)
  float* zp = (float*)(ws + 129503232ull);        // 256KB

  k_prep<<<8960, 256, 0, stream>>>(hidden, Wq, Wk, Wv, hb, wt);
  k_gemm2<<<768, 512, 0, stream>>>(hb, wt, bq, bk, bv, qb, kb, vb, ql, kl);
  k_k2<<<64, 256, 0, stream>>>(ql, kl, k2t, stats, klb);
  k_mid<<<576, 512, 0, stream>>>(k2t, stats, pinvb, ql, kb, vb, nvp, zp);
  k_pnv<<<64, 256, 0, stream>>>(pinvb, nvp, zp, Mtb);
  k_out<<<4096, 256, 0, stream>>>(qb, vb, klb, Mtb, cw, out);
  (void)in_sizes; (void)n_in; (void)out_size; (void)ws_size;
}

// Round 9
// 318.925 us; speedup vs baseline: 1.0023x; 1.0023x over previous
//
#include <hip/hip_runtime.h>
#include <stdint.h>

typedef unsigned short u16;
typedef float f32x4 __attribute__((ext_vector_type(4)));
typedef __bf16 bf16x8 __attribute__((ext_vector_type(8)));
typedef u16 u16x8 __attribute__((ext_vector_type(8)));
typedef u16 u16x4 __attribute__((ext_vector_type(4)));

#define SCALE_QK 0.35355339059327373f

#define BAR() asm volatile("s_barrier" ::: "memory")
#define WAIT_LGKM0() do { asm volatile("s_waitcnt lgkmcnt(0)" ::: "memory"); __builtin_amdgcn_sched_barrier(0); } while (0)
#define WAIT_VM(n) do { asm volatile("s_waitcnt vmcnt(" #n ")" ::: "memory"); __builtin_amdgcn_sched_barrier(0); } while (0)

__device__ __forceinline__ u16 f2bf(float f) {
  union { float f; uint32_t u; } x; x.f = f;
  uint32_t r = x.u + 0x7fffu + ((x.u >> 16) & 1u);
  return (u16)(r >> 16);
}
__device__ __forceinline__ float bf2f(u16 h) {
  union { uint32_t u; float f; } x; x.u = ((uint32_t)h) << 16;
  return x.f;
}
__device__ __forceinline__ void gload16(const void* g, void* l) {
  __builtin_amdgcn_global_load_lds((const __attribute__((address_space(1))) void*)g,
                                   (__attribute__((address_space(3))) void*)l, 16, 0, 0);
}
__device__ __forceinline__ bf16x8 ld_f32_to_bf8(const float* p) {
  f32x4 a = *(const f32x4*)p, b = *(const f32x4*)(p + 4);
  union { u16x8 u; bf16x8 h; } c;
  c.u[0] = f2bf(a[0]); c.u[1] = f2bf(a[1]); c.u[2] = f2bf(a[2]); c.u[3] = f2bf(a[3]);
  c.u[4] = f2bf(b[0]); c.u[5] = f2bf(b[1]); c.u[6] = f2bf(b[2]); c.u[7] = f2bf(b[3]);
  return c.h;
}

// ---------------- merged prep: hidden->bf16 (blocks 0..8191) + weight transpose (blocks 8192..8959) ----------------
__global__ __launch_bounds__(256) void k_prep(const float* __restrict__ hidden,
                                              const float* __restrict__ Wq, const float* __restrict__ Wk,
                                              const float* __restrict__ Wv,
                                              u16* __restrict__ hb, u16* __restrict__ Wt) {
  __shared__ float tile[64][65];
  const int bx = blockIdx.x;
  const int t = threadIdx.x;
  if (bx < 8192) {
    const size_t i = ((size_t)bx * 256 + t) * 8;
    f32x4 v0 = *(const f32x4*)(hidden + i);
    f32x4 v1 = *(const f32x4*)(hidden + i + 4);
    u16x8 o;
    o[0] = f2bf(v0[0]); o[1] = f2bf(v0[1]); o[2] = f2bf(v0[2]); o[3] = f2bf(v0[3]);
    o[4] = f2bf(v1[0]); o[5] = f2bf(v1[1]); o[6] = f2bf(v1[2]); o[7] = f2bf(v1[3]);
    *(u16x8*)(hb + i) = o;
    return;
  }
  const int bxx = bx - 8192;
  const int w = bxx >> 8, tn = (bxx >> 4) & 15, tk = bxx & 15;
  const float* W = (w == 0) ? Wq : ((w == 1) ? Wk : Wv);
  const int r = t >> 2, c0 = (t & 3) * 16;
  const float* src = W + (size_t)(tk * 64 + r) * 1024 + tn * 64 + c0;
#pragma unroll
  for (int j = 0; j < 16; j += 4) {
    f32x4 x = *(const f32x4*)(src + j);
    tile[r][c0 + j + 0] = x[0]; tile[r][c0 + j + 1] = x[1];
    tile[r][c0 + j + 2] = x[2]; tile[r][c0 + j + 3] = x[3];
  }
  __syncthreads();
  u16* dst = Wt + (size_t)(w * 1024 + tn * 64 + r) * 1024 + tk * 64 + c0;
#pragma unroll
  for (int j = 0; j < 16; ++j) dst[j] = f2bf(tile[c0 + j][r]);
}

// ---------------- 256x256x64 8-wave GEMM, counted-vmcnt pipeline + XCD-aware swizzle ----------------
__device__ __forceinline__ bf16x8 frg(const u16* buf, int row, int ks, int lhi) {
  const int ck = (ks << 2) + lhi;
  return *reinterpret_cast<const bf16x8*>(buf + (row << 6) + ((ck ^ (row & 7)) << 3));
}
__device__ __forceinline__ void issue(const u16* g, int rowbase, int tc, u16* ldsbase, int wid) {
  gload16(g + (((size_t)rowbase) << 10) + tc, ldsbase + ((rowbase + (wid << 3)) << 6));
}
template <int Q>
__device__ __forceinline__ void quad_mfma(const bf16x8 (&af)[2][2], const bf16x8 (&bf)[4][2],
                                          f32x4 (&acc)[8][4]) {
#pragma unroll
  for (int mm = 0; mm < 2; ++mm)
#pragma unroll
    for (int n = 0; n < 4; ++n) {
      acc[Q * 2 + mm][n] = __builtin_amdgcn_mfma_f32_16x16x32_bf16(af[mm][0], bf[n][0], acc[Q * 2 + mm][n], 0, 0, 0);
      acc[Q * 2 + mm][n] = __builtin_amdgcn_mfma_f32_16x16x32_bf16(af[mm][1], bf[n][1], acc[Q * 2 + mm][n], 0, 0, 0);
    }
}
#define LOADA_TO(dst, Q)                                     \
  dst[0][0] = frg(ASr, rA0 + (Q)*32, 0, lhi);                \
  dst[0][1] = frg(ASr, rA0 + (Q)*32, 1, lhi);                \
  dst[1][0] = frg(ASr, rA0 + (Q)*32 + 16, 0, lhi);           \
  dst[1][1] = frg(ASr, rA0 + (Q)*32 + 16, 1, lhi);

__global__ __launch_bounds__(512) void k_gemm2(const u16* __restrict__ A, const u16* __restrict__ Bt,
                                               const float* __restrict__ bq, const float* __restrict__ bk,
                                               const float* __restrict__ bv,
                                               u16* __restrict__ oq, u16* __restrict__ ok, u16* __restrict__ ov,
                                               float* __restrict__ ql, float* __restrict__ kl) {
  __shared__ __align__(16) u16 AS[2][256 * 64];
  __shared__ __align__(16) u16 BS[2][256 * 64];
  __shared__ __align__(16) u16 obuf[8][16][70];
  const int t = threadIdx.x, lane = t & 63, wid = t >> 6;
  const int wm = wid >> 2, wn = wid & 3;
  // XCD-aware swizzle (T1): xcd = id&7 owns bm range [8*xcd, 8*xcd+8), bn varies fastest
  // -> A-tile (0.5MB) reused 12x from the XCD's private L2 instead of L3.
  const int bi = blockIdx.x;
  const int bm = ((bi & 7) << 3) + (bi >> 3) / 12;
  const int bn = (bi >> 3) % 12;
  const int l15 = lane & 15, lhi = lane >> 4;

  const int rowoff = t >> 3;
  const int cswz = (t & 7) ^ (rowoff & 7);
  const u16* aG = A + (((size_t)(bm * 256 + rowoff)) << 10) + (cswz << 3);
  const u16* bG = Bt + (((size_t)(bn * 256 + rowoff)) << 10) + (cswz << 3);

  const int rA0 = wm * 128 + l15;
  const int rB0 = wn * 64 + l15;

  f32x4 acc[8][4];
#pragma unroll
  for (int m = 0; m < 8; ++m)
#pragma unroll
    for (int n = 0; n < 4; ++n) acc[m][n] = (f32x4){0.f, 0.f, 0.f, 0.f};

  // prologue: tile 0 -> buf 0. Order: B x4, A-q01 x2, A-q23 x2.
  issue(bG, 0, 0, BS[0], wid);
  issue(bG, 64, 0, BS[0], wid);
  issue(bG, 128, 0, BS[0], wid);
  issue(bG, 192, 0, BS[0], wid);
  issue(aG, 0, 0, AS[0], wid);
  issue(aG, 128, 0, AS[0], wid);
  issue(aG, 64, 0, AS[0], wid);
  issue(aG, 192, 0, AS[0], wid);
  WAIT_VM(2);  // B + A-q01 landed; A-q23 in flight
  BAR();

  for (int u = 0; u < 15; ++u) {
    const int pu = u & 1;
    const u16* ASr = AS[pu];
    const u16* BSr = BS[pu];
    u16* ASw = AS[pu ^ 1];
    u16* BSw = BS[pu ^ 1];
    const int tc = (u + 1) << 6;
    bf16x8 bfr[4][2];
    bf16x8 afA[2][2], afB[2][2];
    // P0: read B(8) + A-q0 + A-q1; issue ALL 8 next-tile loads; MFMA q0
#pragma unroll
    for (int n = 0; n < 4; ++n) {
      bfr[n][0] = frg(BSr, rB0 + n * 16, 0, lhi);
      bfr[n][1] = frg(BSr, rB0 + n * 16, 1, lhi);
    }
    LOADA_TO(afA, 0)
    LOADA_TO(afB, 1)
    issue(bG, 0, tc, BSw, wid);
    issue(bG, 64, tc, BSw, wid);
    issue(bG, 128, tc, BSw, wid);
    issue(bG, 192, tc, BSw, wid);
    issue(aG, 0, tc, ASw, wid);
    issue(aG, 128, tc, ASw, wid);
    issue(aG, 64, tc, ASw, wid);
    issue(aG, 192, tc, ASw, wid);
    __builtin_amdgcn_s_setprio(1);
    quad_mfma<0>(afA, bfr, acc);
    __builtin_amdgcn_s_setprio(0);
    WAIT_VM(8);  // cur-tile A-q23 landed (8 next-tile loads remain in flight)
    BAR();
    // P1: read A-q2; MFMA q1
    LOADA_TO(afA, 2)
    __builtin_amdgcn_s_setprio(1);
    quad_mfma<1>(afB, bfr, acc);
    __builtin_amdgcn_s_setprio(0);
    // P2: read A-q3; MFMA q2
    LOADA_TO(afB, 3)
    __builtin_amdgcn_s_setprio(1);
    quad_mfma<2>(afA, bfr, acc);
    __builtin_amdgcn_s_setprio(0);
    // P3: MFMA q3
    __builtin_amdgcn_s_setprio(1);
    quad_mfma<3>(afB, bfr, acc);
    __builtin_amdgcn_s_setprio(0);
    WAIT_VM(2);  // next-tile B + A-q01 landed; A-q23 stays in flight
    BAR();       // tile boundary
  }
  // peeled tile 15 (buf 1; 2 loads of its A-q23 still in flight at entry)
  {
    const u16* ASr = AS[1];
    const u16* BSr = BS[1];
    bf16x8 bfr[4][2];
    bf16x8 afA[2][2], afB[2][2];
#pragma unroll
    for (int n = 0; n < 4; ++n) {
      bfr[n][0] = frg(BSr, rB0 + n * 16, 0, lhi);
      bfr[n][1] = frg(BSr, rB0 + n * 16, 1, lhi);
    }
    LOADA_TO(afA, 0)
    LOADA_TO(afB, 1)
    quad_mfma<0>(afA, bfr, acc);
    WAIT_VM(0);
    BAR();
    LOADA_TO(afA, 2)
    quad_mfma<1>(afB, bfr, acc);
    LOADA_TO(afB, 3)
    quad_mfma<2>(afA, bfr, acc);
    quad_mfma<3>(afB, bfr, acc);
  }

  // ---- epilogue: bias+scale, LDS bounce, coalesced stores; fused landmark means ----
  const int which = bn >> 2;
  const float* bias = (which == 0) ? bq : ((which == 1) ? bk : bv);
  u16* op = (which == 0) ? oq : ((which == 1) ? ok : ov);
  const float scl = (which < 2) ? SCALE_QK : 1.0f;
  const int h = ((bn & 3) << 2) + wn;  // wave's single head
  const int rowBase2 = (bm << 8) + (wm << 7);
  const int rl = lhi << 2;
  const int srow = lane >> 2, d0 = (lane & 3) * 16;
  float bb[4];
#pragma unroll
  for (int n = 0; n < 4; ++n) bb[n] = bias[((bn & 3) << 8) + (wn << 6) + n * 16 + l15];
#pragma unroll
  for (int m = 0; m < 8; ++m) {
#pragma unroll
    for (int n = 0; n < 4; ++n)
#pragma unroll
      for (int r = 0; r < 4; ++r)
        obuf[wid][rl + r][n * 16 + l15] = f2bf((acc[m][n][r] + bb[n]) * scl);
    const int gm = rowBase2 + m * 16 + srow;
    const int b_ = gm >> 12, s = gm & 4095;
    u16* dst = op + (((size_t)b_ * 16 + h) * 4096 + s) * 64 + d0;
    *(u16x8*)dst = *(const u16x8*)&obuf[wid][srow][d0];
    *(u16x8*)(dst + 8) = *(const u16x8*)&obuf[wid][srow][d0 + 8];
  }
  // landmark segment means (q/k only)
  if (which < 2) {
    float* lmp = (which == 0) ? ql : kl;
    const int bh = ((bm >> 4) << 4) + h;
#pragma unroll
    for (int sg = 0; sg < 2; ++sg) {
#pragma unroll
      for (int n = 0; n < 4; ++n) {
        float s = 0.f;
#pragma unroll
        for (int mi = 0; mi < 4; ++mi)
#pragma unroll
          for (int r = 0; r < 4; ++r) s += (acc[sg * 4 + mi][n][r] + bb[n]) * scl;
        s += __shfl_xor(s, 16, 64);
        s += __shfl_xor(s, 32, 64);
        if (lhi == 0) {
          const int lseg = ((bm & 15) << 2) + (wm << 1) + sg;
          lmp[(size_t)bh * 4096 + lseg * 64 + n * 16 + l15] = s * 0.015625f;
        }
      }
    }
  }
}

// ---------------- kernel_2 = softmax(ql@kl^T); k2t + colmax; also emit klb bf16 ----------------
__global__ __launch_bounds__(256) void k_k2(const float* __restrict__ ql, const float* __restrict__ kl,
                                            float* __restrict__ k2t, float* __restrict__ colmax,
                                            u16* __restrict__ klb) {
  __shared__ __align__(16) float qlT[64 * 68];
  __shared__ __align__(16) float klT[64 * 68];
  __shared__ __align__(16) float sc[64 * 68];
  const int bh = blockIdx.x, t = threadIdx.x;
  {
    const int r = t >> 2, c0 = (t & 3) * 16;
    const float* qp = ql + (size_t)bh * 4096 + r * 64 + c0;
    const float* kp = kl + (size_t)bh * 4096 + r * 64 + c0;
    u16* kb_ = klb + (size_t)bh * 4096 + r * 64 + c0;
#pragma unroll
    for (int j = 0; j < 16; ++j) {
      qlT[(c0 + j) * 68 + r] = qp[j];
      const float kv = kp[j];
      klT[(c0 + j) * 68 + r] = kv;
      kb_[j] = f2bf(kv);
    }
  }
  __syncthreads();
  {
    const int mg = (t >> 4) * 4, lg = (t & 15) * 4;
    float acc[4][4];
#pragma unroll
    for (int i = 0; i < 4; ++i)
#pragma unroll
      for (int j = 0; j < 4; ++j) acc[i][j] = 0.f;
    for (int d0 = 0; d0 < 64; ++d0) {
      f32x4 x = *(const f32x4*)&qlT[d0 * 68 + mg];
      f32x4 y = *(const f32x4*)&klT[d0 * 68 + lg];
#pragma unroll
      for (int i = 0; i < 4; ++i)
#pragma unroll
        for (int j = 0; j < 4; ++j) acc[i][j] += x[i] * y[j];
    }
#pragma unroll
    for (int i = 0; i < 4; ++i)
#pragma unroll
      for (int j = 0; j < 4; ++j) sc[(mg + i) * 68 + lg + j] = acc[i][j];
  }
  __syncthreads();
  if (t < 64) {
    float mx = -1e30f;
    for (int l = 0; l < 64; ++l) mx = fmaxf(mx, sc[t * 68 + l]);
    float sum = 0.f;
    for (int l = 0; l < 64; ++l) { float e = __expf(sc[t * 68 + l] - mx); sc[t * 68 + l] = e; sum += e; }
    const float inv = 1.0f / sum;
    for (int l = 0; l < 64; ++l) sc[t * 68 + l] *= inv;
  }
  __syncthreads();
  {
    const int r = t >> 2, c0 = (t & 3) * 16;
    float* ot = k2t + (size_t)bh * 4096 + r * 64 + c0;
#pragma unroll
    for (int j = 0; j < 16; ++j) ot[j] = sc[(c0 + j) * 68 + r];
  }
  if (t < 64) {
    float s = 0.f;
    for (int m = 0; m < 64; ++m) s += sc[m * 68 + t];
    for (int off = 32; off; off >>= 1) s = fmaxf(s, __shfl_down(s, off, 64));
    if (t == 0) colmax[bh] = s;
  }
}

// ---------------- merged mid: blocks 0..63 = pinv (XOR-swizzled LDS), 64..575 = s3+nv ----------------
__device__ __forceinline__ int pidx(int row, int c) {
  return (row << 6) + ((((c >> 2) ^ (row & 15)) << 2) | (c & 3));
}
__device__ __forceinline__ void mm64s(const float* __restrict__ X, const float* __restrict__ Y,
                                      int row, int c0, float* __restrict__ acc) {
#pragma unroll
  for (int j = 0; j < 8; ++j) acc[j] = 0.f;
  for (int kc = 0; kc < 16; ++kc) {
    f32x4 xq = *(const f32x4*)&X[pidx(row, kc << 2)];
#pragma unroll
    for (int kk = 0; kk < 4; ++kk) {
      const int k = (kc << 2) + kk;
      f32x4 y0 = *(const f32x4*)&Y[pidx(k, c0)];
      f32x4 y1 = *(const f32x4*)&Y[pidx(k, c0 + 4)];
      const float x = xq[kk];
#pragma unroll
      for (int j = 0; j < 4; ++j) { acc[j] += x * y0[j]; acc[4 + j] += x * y1[j]; }
    }
  }
}

__global__ __launch_bounds__(512) void k_mid(const float* __restrict__ k2t, const float* __restrict__ colmax,
                                             float* __restrict__ pinv,
                                             const float* __restrict__ ql, const u16* __restrict__ kb,
                                             const u16* __restrict__ vb,
                                             float* __restrict__ nvp, float* __restrict__ zp) {
  __shared__ __align__(16) char smem_s[81920];
  __shared__ float gsh;
  const int t = threadIdx.x;
  if (blockIdx.x < 64) {
    // ======== pinv: 6 Newton-Schulz iterations, all LDS XOR-swizzled [64][64] f32 ========
    float* aS = (float*)smem_s;        // a (normal layout)
    float* vl = aS + 4096;             // val
    float* kv = vl + 4096;
    float* t1 = kv + 4096;
    float* t2 = t1 + 4096;
    const int bh = blockIdx.x;
    const float* aT = k2t + (size_t)bh * 4096;  // aT[k][r] = a[r][k]
    if (t < 64) {
      float v = colmax[t];
      for (int off = 32; off; off >>= 1) v = fmaxf(v, __shfl_down(v, off, 64));
      if (t == 0) gsh = v;
    }
    const int row = t >> 3, c0 = (t & 7) << 3;
    // stage a into LDS: aS[r][k] = aT[k*64+r]
#pragma unroll
    for (int j = 0; j < 8; ++j) {
      const int i = t * 8 + j;
      aS[pidx(i & 63, i >> 6)] = aT[i];
    }
    __syncthreads();
    const float ginv = 1.0f / gsh;
    {
      f32x4 v0 = *(const f32x4*)(aT + row * 64 + c0);
      f32x4 v1 = *(const f32x4*)(aT + row * 64 + c0 + 4);
      v0 *= ginv; v1 *= ginv;
      *(f32x4*)&vl[pidx(row, c0)] = v0;       // val0[r][c] = aT[r][c]/g
      *(f32x4*)&vl[pidx(row, c0 + 4)] = v1;
    }
    __syncthreads();
    float acc[8];
    for (int it = 0; it < 6; ++it) {
      mm64s(aS, vl, row, c0, acc);            // kv = a @ val
#pragma unroll
      for (int j = 0; j < 8; ++j) kv[pidx(row, c0 + j)] = acc[j];
      __syncthreads();
#pragma unroll
      for (int j = 0; j < 8; ++j) {           // t1 = 7I - kv
        const int c = c0 + j;
        t1[pidx(row, c)] = ((row == c) ? 7.0f : 0.0f) - kv[pidx(row, c)];
      }
      __syncthreads();
      mm64s(kv, t1, row, c0, acc);            // t2 = 15I - kv@t1
#pragma unroll
      for (int j = 0; j < 8; ++j) {
        const int c = c0 + j;
        t2[pidx(row, c)] = ((row == c) ? 15.0f : 0.0f) - acc[j];
      }
      __syncthreads();
      mm64s(kv, t2, row, c0, acc);            // t1 = 13I - kv@t2
#pragma unroll
      for (int j = 0; j < 8; ++j) {
        const int c = c0 + j;
        t1[pidx(row, c)] = ((row == c) ? 13.0f : 0.0f) - acc[j];
      }
      __syncthreads();
      mm64s(vl, t1, row, c0, acc);            // t2 = 0.25 * val@t1
#pragma unroll
      for (int j = 0; j < 8; ++j) t2[pidx(row, c0 + j)] = 0.25f * acc[j];
      __syncthreads();
#pragma unroll
      for (int j = 0; j < 8; ++j) vl[pidx(row, c0 + j)] = t2[pidx(row, c0 + j)];  // val = t2
      __syncthreads();
    }
    {
      f32x4 o0 = *(const f32x4*)&vl[pidx(row, c0)];
      f32x4 o1 = *(const f32x4*)&vl[pidx(row, c0 + 4)];
      *(f32x4*)(pinv + (size_t)bh * 4096 + row * 64 + c0) = o0;
      *(f32x4*)(pinv + (size_t)bh * 4096 + row * 64 + c0 + 4) = o1;
    }
    return;
  }
  // ======== s3+nv: 512 threads = 2 S-halves x 4 L-quarter waves ========
  u16* VTs = (u16*)smem_s;                    // [2 buf][2 half][64][72]
  u16* els = (u16*)(smem_s + 36864);          // [8][16][72]
  const int id = (int)blockIdx.x - 64;
  const int bh = id & 63, scn = id >> 6;      // scn in [0,8)
  const int lane = t & 63, w = t >> 6;
  const int wq = w & 3, half = w >> 2;
  const int l15 = lane & 15, kg = (lane >> 4) << 3, rl = (lane >> 4) << 2;
  const float* aRow = ql + (size_t)bh * 4096 + (wq * 16 + l15) * 64 + kg;
  bf16x8 aql[2];
  aql[0] = ld_f32_to_bf8(aRow);
  aql[1] = ld_f32_to_bf8(aRow + 32);
  f32x4 accv[4];
#pragma unroll
  for (int n = 0; n < 4; ++n) accv[n] = (f32x4){0.f, 0.f, 0.f, 0.f};
  float zacc[4] = {0.f, 0.f, 0.f, 0.f};
  const int sBase = scn * 512 + half * 256;
  u16* VT0 = VTs + ((size_t)(0 * 2 + half) * 64) * 72;
  u16* VT1 = VTs + ((size_t)(1 * 2 + half) * 64) * 72;
  u16* elw = els + ((size_t)w * 16) * 72;
  // preload sub 0 into VT0
  {
    const u16* vp = vb + ((size_t)bh * 4096 + sBase + lane) * 64 + wq * 16;
    u16x8 h0 = *(const u16x8*)vp, h1 = *(const u16x8*)(vp + 8);
#pragma unroll
    for (int j = 0; j < 8; ++j) {
      VT0[(wq * 16 + j) * 72 + lane] = h0[j];
      VT0[(wq * 16 + 8 + j) * 72 + lane] = h1[j];
    }
  }
  __syncthreads();
  for (int sub = 0; sub < 4; ++sub) {
    const int s0 = sBase + sub * 64;
    u16x8 hn0 = {0, 0, 0, 0, 0, 0, 0, 0}, hn1 = {0, 0, 0, 0, 0, 0, 0, 0};
    if (sub < 3) {  // prefetch next V tile into regs
      const u16* vpn = vb + ((size_t)bh * 4096 + s0 + 64 + lane) * 64 + wq * 16;
      hn0 = *(const u16x8*)vpn; hn1 = *(const u16x8*)(vpn + 8);
    }
    const u16* bRow = kb + ((size_t)bh * 4096 + s0 + l15) * 64 + kg;
    f32x4 e[4];
#pragma unroll
    for (int n = 0; n < 4; ++n) e[n] = (f32x4){0.f, 0.f, 0.f, 0.f};
#pragma unroll
    for (int ks = 0; ks < 2; ++ks)
#pragma unroll
      for (int n = 0; n < 4; ++n) {
        bf16x8 bk_ = *reinterpret_cast<const bf16x8*>(bRow + n * 1024 + ks * 32);
        e[n] = __builtin_amdgcn_mfma_f32_16x16x32_bf16(aql[ks], bk_, e[n], 0, 0, 0);
      }
#pragma unroll
    for (int n = 0; n < 4; ++n)
#pragma unroll
      for (int r = 0; r < 4; ++r) {
        const float v = __expf(e[n][r]);
        zacc[r] += v;
        elw[(rl + r) * 72 + n * 16 + l15] = f2bf(v);
      }
    if (sub < 3) {
      u16* VTn = ((sub + 1) & 1) ? VT1 : VT0;
#pragma unroll
      for (int j = 0; j < 8; ++j) {
        VTn[(wq * 16 + j) * 72 + lane] = hn0[j];
        VTn[(wq * 16 + 8 + j) * 72 + lane] = hn1[j];
      }
    }
    WAIT_LGKM0();  // own e_lds + VT writes complete
    const u16* VTc = (sub & 1) ? VT1 : VT0;
#pragma unroll
    for (int ks = 0; ks < 2; ++ks) {
      bf16x8 af = *reinterpret_cast<const bf16x8*>(&elw[l15 * 72 + kg + ks * 32]);
#pragma unroll
      for (int n = 0; n < 4; ++n) {
        bf16x8 bf_ = *reinterpret_cast<const bf16x8*>(&VTc[(n * 16 + l15) * 72 + kg + ks * 32]);
        accv[n] = __builtin_amdgcn_mfma_f32_16x16x32_bf16(af, bf_, accv[n], 0, 0, 0);
      }
    }
    BAR();  // publish next VT buf; WAR fence on current
  }
  const int p = scn * 2 + half;
#pragma unroll
  for (int r = 0; r < 4; ++r)
#pragma unroll
    for (int n = 0; n < 4; ++n)
      nvp[(((size_t)p * 64 + bh) * 64 + wq * 16 + rl + r) * 64 + n * 16 + l15] = accv[n][r];
#pragma unroll
  for (int r = 0; r < 4; ++r) {
    float s = zacc[r];
    s += __shfl_xor(s, 1, 64); s += __shfl_xor(s, 2, 64);
    s += __shfl_xor(s, 4, 64); s += __shfl_xor(s, 8, 64);
    if (l15 == 0) zp[((size_t)p * 64 + bh) * 64 + wq * 16 + rl + r] = s;
  }
}

// ---------------- M^T (bf16) = (pinv @ (sum(nvp)/sum(zp)))^T ----------------
__global__ __launch_bounds__(256) void k_pnv(const float* __restrict__ pinv, const float* __restrict__ nvp,
                                             const float* __restrict__ zp, u16* __restrict__ Mtb) {
  __shared__ __align__(16) float XT[64 * 68];
  __shared__ __align__(16) float Y[64 * 68];
  const int bh = blockIdx.x, t = threadIdx.x;
  {
    const int r = t >> 2, c0 = (t & 3) * 16;
    const float* pp = pinv + (size_t)bh * 4096 + r * 64 + c0;
#pragma unroll
    for (int j = 0; j < 16; ++j) XT[(c0 + j) * 68 + r] = pp[j];
    float zs = 0.f;
#pragma unroll
    for (int p = 0; p < 16; ++p) zs += zp[((size_t)p * 64 + bh) * 64 + r];
    const float iz = 1.0f / zs;
#pragma unroll
    for (int j = 0; j < 16; ++j) {
      float s = 0.f;
#pragma unroll
      for (int p = 0; p < 16; ++p) s += nvp[(((size_t)p * 64 + bh) * 64 + r) * 64 + c0 + j];
      Y[r * 68 + c0 + j] = s * iz;
    }
  }
  __syncthreads();
  const int rg = (t >> 4) * 4, cg = (t & 15) * 4;
  float acc[4][4];
#pragma unroll
  for (int i = 0; i < 4; ++i)
#pragma unroll
    for (int j = 0; j < 4; ++j) acc[i][j] = 0.f;
  for (int k = 0; k < 64; ++k) {
    f32x4 x = *(const f32x4*)&XT[k * 68 + rg];
    f32x4 y = *(const f32x4*)&Y[k * 68 + cg];
#pragma unroll
    for (int i = 0; i < 4; ++i)
#pragma unroll
      for (int j = 0; j < 4; ++j) acc[i][j] += x[i] * y[j];
  }
#pragma unroll
  for (int j = 0; j < 4; ++j) {
    u16x4 o = {f2bf(acc[0][j]), f2bf(acc[1][j]), f2bf(acc[2][j]), f2bf(acc[3][j])};
    *(u16x4*)&Mtb[(size_t)bh * 4096 + (cg + j) * 64 + rg] = o;
  }
}

// ---------------- final: softmax(q·kl^T) @ M^T + depthwise conv ----------------
__global__ __launch_bounds__(256) void k_out(const u16* __restrict__ qb, const u16* __restrict__ vb,
                                             const u16* __restrict__ klb, const u16* __restrict__ Mtb,
                                             const float* __restrict__ cw, float* __restrict__ out) {
  __shared__ __align__(16) u16 P_lds[4][16][72];
  __shared__ __align__(16) u16 vtile_t[64][100];  // [d][row]
  __shared__ float wsh[33];
  const int bid = blockIdx.x;
  const int bh = bid >> 6, st = bid & 63;
  const int b = bh >> 4, h = bh & 15;
  const int t = threadIdx.x, lane = t & 63, w = t >> 6;
  const int sbase = st * 64;
  const int l15 = lane & 15, kg = (lane >> 4) << 3, rl = (lane >> 4) << 2;

  if (t < 33) wsh[t] = cw[h * 33 + t];
  for (int idx = t; idx < 96 * 8; idx += 256) {
    const int row = idx >> 3, c8 = idx & 7;
    const int sg = sbase + row - 16;
    u16x8 val = {0, 0, 0, 0, 0, 0, 0, 0};
    if (sg >= 0 && sg < 4096) val = *(const u16x8*)(vb + ((size_t)bh * 4096 + sg) * 64 + c8 * 8);
#pragma unroll
    for (int j = 0; j < 8; ++j) vtile_t[c8 * 8 + j][row] = val[j];
  }

  f32x4 c1[4];
#pragma unroll
  for (int n = 0; n < 4; ++n) c1[n] = (f32x4){0.f, 0.f, 0.f, 0.f};
  {
    const u16* aRow = qb + ((size_t)bh * 4096 + sbase + w * 16 + l15) * 64 + kg;
    const u16* kRow = klb + (size_t)bh * 4096 + l15 * 64 + kg;
#pragma unroll
    for (int ks = 0; ks < 2; ++ks) {
      bf16x8 af = *reinterpret_cast<const bf16x8*>(aRow + ks * 32);
#pragma unroll
      for (int n = 0; n < 4; ++n) {
        bf16x8 bf_ = *reinterpret_cast<const bf16x8*>(kRow + n * 1024 + ks * 32);
        c1[n] = __builtin_amdgcn_mfma_f32_16x16x32_bf16(af, bf_, c1[n], 0, 0, 0);
      }
    }
  }
  float invZ[4];
  {
    float z[4] = {0.f, 0.f, 0.f, 0.f};
#pragma unroll
    for (int n = 0; n < 4; ++n)
#pragma unroll
      for (int r = 0; r < 4; ++r) { float v = __expf(c1[n][r]); c1[n][r] = v; z[r] += v; }
#pragma unroll
    for (int r = 0; r < 4; ++r) {
      float s = z[r];
      s += __shfl_xor(s, 1, 64); s += __shfl_xor(s, 2, 64);
      s += __shfl_xor(s, 4, 64); s += __shfl_xor(s, 8, 64);
      invZ[r] = 1.0f / s;
    }
#pragma unroll
    for (int n = 0; n < 4; ++n)
#pragma unroll
      for (int r = 0; r < 4; ++r)
        P_lds[w][rl + r][n * 16 + l15] = f2bf(c1[n][r]);
  }
  __syncthreads();
  f32x4 c2[4];
#pragma unroll
  for (int n = 0; n < 4; ++n) c2[n] = (f32x4){0.f, 0.f, 0.f, 0.f};
  {
    const u16* mRow = Mtb + (size_t)bh * 4096 + l15 * 64 + kg;
#pragma unroll
    for (int ks = 0; ks < 2; ++ks) {
      bf16x8 af = *reinterpret_cast<const bf16x8*>(&P_lds[w][l15][kg + ks * 32]);
#pragma unroll
      for (int n = 0; n < 4; ++n) {
        bf16x8 bf_ = *reinterpret_cast<const bf16x8*>(mRow + n * 1024 + ks * 32);
        c2[n] = __builtin_amdgcn_mfma_f32_16x16x32_bf16(af, bf_, c2[n], 0, 0, 0);
      }
    }
  }
  const int base = w * 16 + rl;
#pragma unroll
  for (int n = 0; n < 4; ++n) {
    const int d = n * 16 + l15;
    float vcol[36];
#pragma unroll
    for (int k8 = 0; k8 < 9; ++k8) {
      u16x4 vq = *(const u16x4*)&vtile_t[d][base + k8 * 4];
      vcol[k8 * 4 + 0] = bf2f(vq[0]); vcol[k8 * 4 + 1] = bf2f(vq[1]);
      vcol[k8 * 4 + 2] = bf2f(vq[2]); vcol[k8 * 4 + 3] = bf2f(vq[3]);
    }
    float cv[4] = {0.f, 0.f, 0.f, 0.f};
#pragma unroll
    for (int jt = 0; jt < 33; ++jt) {
      const float ww = wsh[jt];
#pragma unroll
      for (int r = 0; r < 4; ++r) cv[r] += ww * vcol[r + jt];
    }
#pragma unroll
    for (int r = 0; r < 4; ++r) {
      const int sgl = sbase + base + r;
      out[((size_t)b * 4096 + sgl) * 1024 + h * 64 + d] = c2[n][r] * invZ[r] + cv[r];
    }
  }
}

extern "C" void kernel_launch(void* const* d_in, const int* in_sizes, int n_in,
                              void* d_out, int out_size, void* d_ws, size_t ws_size,
                              hipStream_t stream) {
  const float* hidden = (const float*)d_in[0];
  const float* Wq = (const float*)d_in[1];
  const float* bq = (const float*)d_in[2];
  const float* Wk = (const float*)d_in[3];
  const float* bk = (const float*)d_in[4];
  const float* Wv = (const float*)d_in[5];
  const float* bv = (const float*)d_in[6];
  const float* cw = (const float*)d_in[7];
  float* out = (float*)d_out;

  char* ws = (char*)d_ws;
  u16* qb = (u16*)(ws);                           // 32MB
  u16* kb = (u16*)(ws + 33554432ull);             // 32MB
  u16* vb = (u16*)(ws + 67108864ull);             // 32MB
  float* ql = (float*)(ws + 100663296ull);        // 1MB
  float* kl = (float*)(ws + 101711872ull);        // 1MB
  float* k2t = (float*)(ws + 102760448ull);       // 1MB
  float* pinvb = (float*)(ws + 103809024ull);     // 1MB
  u16* Mtb = (u16*)(ws + 104857600ull);           // 512KB
  u16* klb = (u16*)(ws + 105381888ull);           // 1MB
  float* stats = (float*)(ws + 106430464ull);     // 4KB
  u16* wt = (u16*)(ws + 106434560ull);            // 6MB, dead after k_gemm2
  u16* hb = (u16*)(ws + 112726016ull);            // 32MB, dead after k_gemm2
  float* nvp = (float*)(ws + 112726016ull);       // 16.8MB, aliases hb (dead)
  float* zp = (float*)(ws + 129503232ull);        // 256KB

  k_prep<<<8960, 256, 0, stream>>>(hidden, Wq, Wk, Wv, hb, wt);
  k_gemm2<<<768, 512, 0, stream>>>(hb, wt, bq, bk, bv, qb, kb, vb, ql, kl);
  k_k2<<<64, 256, 0, stream>>>(ql, kl, k2t, stats, klb);
  k_mid<<<576, 512, 0, stream>>>(k2t, stats, pinvb, ql, kb, vb, nvp, zp);
  k_pnv<<<64, 256, 0, stream>>>(pinvb, nvp, zp, Mtb);
  k_out<<<4096, 256, 0, stream>>>(qb, vb, klb, Mtb, cw, out);
  (void)in_sizes; (void)n_in; (void)out_size; (void)ws_size;
}

// Round 10
// 318.866 us; speedup vs baseline: 1.0024x; 1.0002x over previous
//
#include <hip/hip_runtime.h>
#include <stdint.h>

typedef unsigned short u16;
typedef float f32x4 __attribute__((ext_vector_type(4)));
typedef __bf16 bf16x8 __attribute__((ext_vector_type(8)));
typedef u16 u16x8 __attribute__((ext_vector_type(8)));
typedef u16 u16x4 __attribute__((ext_vector_type(4)));

#define SCALE_QK 0.35355339059327373f

#define BAR() asm volatile("s_barrier" ::: "memory")
#define WAIT_LGKM0() do { asm volatile("s_waitcnt lgkmcnt(0)" ::: "memory"); __builtin_amdgcn_sched_barrier(0); } while (0)
#define WAIT_VM(n) do { asm volatile("s_waitcnt vmcnt(" #n ")" ::: "memory"); __builtin_amdgcn_sched_barrier(0); } while (0)

__device__ __forceinline__ u16 f2bf(float f) {
  union { float f; uint32_t u; } x; x.f = f;
  uint32_t r = x.u + 0x7fffu + ((x.u >> 16) & 1u);
  return (u16)(r >> 16);
}
__device__ __forceinline__ float bf2f(u16 h) {
  union { uint32_t u; float f; } x; x.u = ((uint32_t)h) << 16;
  return x.f;
}
__device__ __forceinline__ void gload16(const void* g, void* l) {
  __builtin_amdgcn_global_load_lds((const __attribute__((address_space(1))) void*)g,
                                   (__attribute__((address_space(3))) void*)l, 16, 0, 0);
}
__device__ __forceinline__ bf16x8 ld_f32_to_bf8(const float* p) {
  f32x4 a = *(const f32x4*)p, b = *(const f32x4*)(p + 4);
  union { u16x8 u; bf16x8 h; } c;
  c.u[0] = f2bf(a[0]); c.u[1] = f2bf(a[1]); c.u[2] = f2bf(a[2]); c.u[3] = f2bf(a[3]);
  c.u[4] = f2bf(b[0]); c.u[5] = f2bf(b[1]); c.u[6] = f2bf(b[2]); c.u[7] = f2bf(b[3]);
  return c.h;
}

// ---------------- merged prep: hidden->bf16 (blocks 0..8191) + weight transpose (blocks 8192..8959) ----------------
__global__ __launch_bounds__(256) void k_prep(const float* __restrict__ hidden,
                                              const float* __restrict__ Wq, const float* __restrict__ Wk,
                                              const float* __restrict__ Wv,
                                              u16* __restrict__ hb, u16* __restrict__ Wt) {
  __shared__ float tile[64][65];
  const int bx = blockIdx.x;
  const int t = threadIdx.x;
  if (bx < 8192) {
    const size_t i = ((size_t)bx * 256 + t) * 8;
    f32x4 v0 = *(const f32x4*)(hidden + i);
    f32x4 v1 = *(const f32x4*)(hidden + i + 4);
    u16x8 o;
    o[0] = f2bf(v0[0]); o[1] = f2bf(v0[1]); o[2] = f2bf(v0[2]); o[3] = f2bf(v0[3]);
    o[4] = f2bf(v1[0]); o[5] = f2bf(v1[1]); o[6] = f2bf(v1[2]); o[7] = f2bf(v1[3]);
    *(u16x8*)(hb + i) = o;
    return;
  }
  const int bxx = bx - 8192;
  const int w = bxx >> 8, tn = (bxx >> 4) & 15, tk = bxx & 15;
  const float* W = (w == 0) ? Wq : ((w == 1) ? Wk : Wv);
  const int r = t >> 2, c0 = (t & 3) * 16;
  const float* src = W + (size_t)(tk * 64 + r) * 1024 + tn * 64 + c0;
#pragma unroll
  for (int j = 0; j < 16; j += 4) {
    f32x4 x = *(const f32x4*)(src + j);
    tile[r][c0 + j + 0] = x[0]; tile[r][c0 + j + 1] = x[1];
    tile[r][c0 + j + 2] = x[2]; tile[r][c0 + j + 3] = x[3];
  }
  __syncthreads();
  u16* dst = Wt + (size_t)(w * 1024 + tn * 64 + r) * 1024 + tk * 64 + c0;
#pragma unroll
  for (int j = 0; j < 16; ++j) dst[j] = f2bf(tile[c0 + j][r]);
}

// ---------------- 256x256x64 8-wave GEMM, counted-vmcnt pipeline + XCD-aware swizzle ----------------
__device__ __forceinline__ bf16x8 frg(const u16* buf, int row, int ks, int lhi) {
  const int ck = (ks << 2) + lhi;
  return *reinterpret_cast<const bf16x8*>(buf + (row << 6) + ((ck ^ (row & 7)) << 3));
}
__device__ __forceinline__ void issue(const u16* g, int rowbase, int tc, u16* ldsbase, int wid) {
  gload16(g + (((size_t)rowbase) << 10) + tc, ldsbase + ((rowbase + (wid << 3)) << 6));
}
template <int Q>
__device__ __forceinline__ void quad_mfma(const bf16x8 (&af)[2][2], const bf16x8 (&bf)[4][2],
                                          f32x4 (&acc)[8][4]) {
#pragma unroll
  for (int mm = 0; mm < 2; ++mm)
#pragma unroll
    for (int n = 0; n < 4; ++n) {
      acc[Q * 2 + mm][n] = __builtin_amdgcn_mfma_f32_16x16x32_bf16(af[mm][0], bf[n][0], acc[Q * 2 + mm][n], 0, 0, 0);
      acc[Q * 2 + mm][n] = __builtin_amdgcn_mfma_f32_16x16x32_bf16(af[mm][1], bf[n][1], acc[Q * 2 + mm][n], 0, 0, 0);
    }
}
#define LOADA_TO(dst, Q)                                     \
  dst[0][0] = frg(ASr, rA0 + (Q)*32, 0, lhi);                \
  dst[0][1] = frg(ASr, rA0 + (Q)*32, 1, lhi);                \
  dst[1][0] = frg(ASr, rA0 + (Q)*32 + 16, 0, lhi);           \
  dst[1][1] = frg(ASr, rA0 + (Q)*32 + 16, 1, lhi);

__global__ __launch_bounds__(512) void k_gemm2(const u16* __restrict__ A, const u16* __restrict__ Bt,
                                               const float* __restrict__ bq, const float* __restrict__ bk,
                                               const float* __restrict__ bv,
                                               u16* __restrict__ oq, u16* __restrict__ ok, u16* __restrict__ ov,
                                               float* __restrict__ ql, float* __restrict__ kl) {
  __shared__ __align__(16) u16 AS[2][256 * 64];
  __shared__ __align__(16) u16 BS[2][256 * 64];
  __shared__ __align__(16) u16 obuf[8][16][70];
  const int t = threadIdx.x, lane = t & 63, wid = t >> 6;
  const int wm = wid >> 2, wn = wid & 3;
  // XCD-aware swizzle (T1): xcd = id&7 owns bm range [8*xcd, 8*xcd+8), bn varies fastest
  // -> A-tile (0.5MB) reused 12x from the XCD's private L2 instead of L3.
  const int bi = blockIdx.x;
  const int bm = ((bi & 7) << 3) + (bi >> 3) / 12;
  const int bn = (bi >> 3) % 12;
  const int l15 = lane & 15, lhi = lane >> 4;

  const int rowoff = t >> 3;
  const int cswz = (t & 7) ^ (rowoff & 7);
  const u16* aG = A + (((size_t)(bm * 256 + rowoff)) << 10) + (cswz << 3);
  const u16* bG = Bt + (((size_t)(bn * 256 + rowoff)) << 10) + (cswz << 3);

  const int rA0 = wm * 128 + l15;
  const int rB0 = wn * 64 + l15;

  f32x4 acc[8][4];
#pragma unroll
  for (int m = 0; m < 8; ++m)
#pragma unroll
    for (int n = 0; n < 4; ++n) acc[m][n] = (f32x4){0.f, 0.f, 0.f, 0.f};

  // prologue: tile 0 -> buf 0. Order: B x4, A-q01 x2, A-q23 x2.
  issue(bG, 0, 0, BS[0], wid);
  issue(bG, 64, 0, BS[0], wid);
  issue(bG, 128, 0, BS[0], wid);
  issue(bG, 192, 0, BS[0], wid);
  issue(aG, 0, 0, AS[0], wid);
  issue(aG, 128, 0, AS[0], wid);
  issue(aG, 64, 0, AS[0], wid);
  issue(aG, 192, 0, AS[0], wid);
  WAIT_VM(2);  // B + A-q01 landed; A-q23 in flight
  BAR();

  for (int u = 0; u < 15; ++u) {
    const int pu = u & 1;
    const u16* ASr = AS[pu];
    const u16* BSr = BS[pu];
    u16* ASw = AS[pu ^ 1];
    u16* BSw = BS[pu ^ 1];
    const int tc = (u + 1) << 6;
    bf16x8 bfr[4][2];
    bf16x8 afA[2][2], afB[2][2];
    // P0: read B(8) + A-q0 + A-q1; issue ALL 8 next-tile loads; MFMA q0
#pragma unroll
    for (int n = 0; n < 4; ++n) {
      bfr[n][0] = frg(BSr, rB0 + n * 16, 0, lhi);
      bfr[n][1] = frg(BSr, rB0 + n * 16, 1, lhi);
    }
    LOADA_TO(afA, 0)
    LOADA_TO(afB, 1)
    issue(bG, 0, tc, BSw, wid);
    issue(bG, 64, tc, BSw, wid);
    issue(bG, 128, tc, BSw, wid);
    issue(bG, 192, tc, BSw, wid);
    issue(aG, 0, tc, ASw, wid);
    issue(aG, 128, tc, ASw, wid);
    issue(aG, 64, tc, ASw, wid);
    issue(aG, 192, tc, ASw, wid);
    __builtin_amdgcn_s_setprio(1);
    quad_mfma<0>(afA, bfr, acc);
    __builtin_amdgcn_s_setprio(0);
    WAIT_VM(8);  // cur-tile A-q23 landed (8 next-tile loads remain in flight)
    BAR();
    // P1: read A-q2; MFMA q1
    LOADA_TO(afA, 2)
    __builtin_amdgcn_s_setprio(1);
    quad_mfma<1>(afB, bfr, acc);
    __builtin_amdgcn_s_setprio(0);
    // P2: read A-q3; MFMA q2
    LOADA_TO(afB, 3)
    __builtin_amdgcn_s_setprio(1);
    quad_mfma<2>(afA, bfr, acc);
    __builtin_amdgcn_s_setprio(0);
    // P3: MFMA q3
    __builtin_amdgcn_s_setprio(1);
    quad_mfma<3>(afB, bfr, acc);
    __builtin_amdgcn_s_setprio(0);
    WAIT_VM(2);  // next-tile B + A-q01 landed; A-q23 stays in flight
    BAR();       // tile boundary
  }
  // peeled tile 15 (buf 1; 2 loads of its A-q23 still in flight at entry)
  {
    const u16* ASr = AS[1];
    const u16* BSr = BS[1];
    bf16x8 bfr[4][2];
    bf16x8 afA[2][2], afB[2][2];
#pragma unroll
    for (int n = 0; n < 4; ++n) {
      bfr[n][0] = frg(BSr, rB0 + n * 16, 0, lhi);
      bfr[n][1] = frg(BSr, rB0 + n * 16, 1, lhi);
    }
    LOADA_TO(afA, 0)
    LOADA_TO(afB, 1)
    quad_mfma<0>(afA, bfr, acc);
    WAIT_VM(0);
    BAR();
    LOADA_TO(afA, 2)
    quad_mfma<1>(afB, bfr, acc);
    LOADA_TO(afB, 3)
    quad_mfma<2>(afA, bfr, acc);
    quad_mfma<3>(afB, bfr, acc);
  }

  // ---- epilogue: bias+scale, LDS bounce, coalesced stores; fused landmark means ----
  const int which = bn >> 2;
  const float* bias = (which == 0) ? bq : ((which == 1) ? bk : bv);
  u16* op = (which == 0) ? oq : ((which == 1) ? ok : ov);
  const float scl = (which < 2) ? SCALE_QK : 1.0f;
  const int h = ((bn & 3) << 2) + wn;  // wave's single head
  const int rowBase2 = (bm << 8) + (wm << 7);
  const int rl = lhi << 2;
  const int srow = lane >> 2, d0 = (lane & 3) * 16;
  float bb[4];
#pragma unroll
  for (int n = 0; n < 4; ++n) bb[n] = bias[((bn & 3) << 8) + (wn << 6) + n * 16 + l15];
#pragma unroll
  for (int m = 0; m < 8; ++m) {
#pragma unroll
    for (int n = 0; n < 4; ++n)
#pragma unroll
      for (int r = 0; r < 4; ++r)
        obuf[wid][rl + r][n * 16 + l15] = f2bf((acc[m][n][r] + bb[n]) * scl);
    const int gm = rowBase2 + m * 16 + srow;
    const int b_ = gm >> 12, s = gm & 4095;
    u16* dst = op + (((size_t)b_ * 16 + h) * 4096 + s) * 64 + d0;
    *(u16x8*)dst = *(const u16x8*)&obuf[wid][srow][d0];
    *(u16x8*)(dst + 8) = *(const u16x8*)&obuf[wid][srow][d0 + 8];
  }
  // landmark segment means (q/k only)
  if (which < 2) {
    float* lmp = (which == 0) ? ql : kl;
    const int bh = ((bm >> 4) << 4) + h;
#pragma unroll
    for (int sg = 0; sg < 2; ++sg) {
#pragma unroll
      for (int n = 0; n < 4; ++n) {
        float s = 0.f;
#pragma unroll
        for (int mi = 0; mi < 4; ++mi)
#pragma unroll
          for (int r = 0; r < 4; ++r) s += (acc[sg * 4 + mi][n][r] + bb[n]) * scl;
        s += __shfl_xor(s, 16, 64);
        s += __shfl_xor(s, 32, 64);
        if (lhi == 0) {
          const int lseg = ((bm & 15) << 2) + (wm << 1) + sg;
          lmp[(size_t)bh * 4096 + lseg * 64 + n * 16 + l15] = s * 0.015625f;
        }
      }
    }
  }
}

// ---------------- kernel_2 = softmax(ql@kl^T); k2t + colmax; also emit klb bf16 ----------------
__global__ __launch_bounds__(256) void k_k2(const float* __restrict__ ql, const float* __restrict__ kl,
                                            float* __restrict__ k2t, float* __restrict__ colmax,
                                            u16* __restrict__ klb) {
  __shared__ __align__(16) float qlT[64 * 68];
  __shared__ __align__(16) float klT[64 * 68];
  __shared__ __align__(16) float sc[64 * 68];
  const int bh = blockIdx.x, t = threadIdx.x;
  {
    const int r = t >> 2, c0 = (t & 3) * 16;
    const float* qp = ql + (size_t)bh * 4096 + r * 64 + c0;
    const float* kp = kl + (size_t)bh * 4096 + r * 64 + c0;
    u16* kb_ = klb + (size_t)bh * 4096 + r * 64 + c0;
#pragma unroll
    for (int j = 0; j < 16; ++j) {
      qlT[(c0 + j) * 68 + r] = qp[j];
      const float kv = kp[j];
      klT[(c0 + j) * 68 + r] = kv;
      kb_[j] = f2bf(kv);
    }
  }
  __syncthreads();
  {
    const int mg = (t >> 4) * 4, lg = (t & 15) * 4;
    float acc[4][4];
#pragma unroll
    for (int i = 0; i < 4; ++i)
#pragma unroll
      for (int j = 0; j < 4; ++j) acc[i][j] = 0.f;
    for (int d0 = 0; d0 < 64; ++d0) {
      f32x4 x = *(const f32x4*)&qlT[d0 * 68 + mg];
      f32x4 y = *(const f32x4*)&klT[d0 * 68 + lg];
#pragma unroll
      for (int i = 0; i < 4; ++i)
#pragma unroll
        for (int j = 0; j < 4; ++j) acc[i][j] += x[i] * y[j];
    }
#pragma unroll
    for (int i = 0; i < 4; ++i)
#pragma unroll
      for (int j = 0; j < 4; ++j) sc[(mg + i) * 68 + lg + j] = acc[i][j];
  }
  __syncthreads();
  if (t < 64) {
    float mx = -1e30f;
    for (int l = 0; l < 64; ++l) mx = fmaxf(mx, sc[t * 68 + l]);
    float sum = 0.f;
    for (int l = 0; l < 64; ++l) { float e = __expf(sc[t * 68 + l] - mx); sc[t * 68 + l] = e; sum += e; }
    const float inv = 1.0f / sum;
    for (int l = 0; l < 64; ++l) sc[t * 68 + l] *= inv;
  }
  __syncthreads();
  {
    const int r = t >> 2, c0 = (t & 3) * 16;
    float* ot = k2t + (size_t)bh * 4096 + r * 64 + c0;
#pragma unroll
    for (int j = 0; j < 16; ++j) ot[j] = sc[(c0 + j) * 68 + r];
  }
  if (t < 64) {
    float s = 0.f;
    for (int m = 0; m < 64; ++m) s += sc[m * 68 + t];
    for (int off = 32; off; off >>= 1) s = fmaxf(s, __shfl_down(s, off, 64));
    if (t == 0) colmax[bh] = s;
  }
}

// ---------------- merged mid: blocks 0..63 = pinv (XOR-swizzled LDS), 64..575 = s3+nv ----------------
__device__ __forceinline__ int pidx(int row, int c) {
  return (row << 6) + ((((c >> 2) ^ (row & 15)) << 2) | (c & 3));
}
__device__ __forceinline__ void mm64s(const float* __restrict__ X, const float* __restrict__ Y,
                                      int row, int c0, float* __restrict__ acc) {
#pragma unroll
  for (int j = 0; j < 8; ++j) acc[j] = 0.f;
  for (int kc = 0; kc < 16; ++kc) {
    f32x4 xq = *(const f32x4*)&X[pidx(row, kc << 2)];
#pragma unroll
    for (int kk = 0; kk < 4; ++kk) {
      const int k = (kc << 2) + kk;
      f32x4 y0 = *(const f32x4*)&Y[pidx(k, c0)];
      f32x4 y1 = *(const f32x4*)&Y[pidx(k, c0 + 4)];
      const float x = xq[kk];
#pragma unroll
      for (int j = 0; j < 4; ++j) { acc[j] += x * y0[j]; acc[4 + j] += x * y1[j]; }
    }
  }
}

__global__ __launch_bounds__(512) void k_mid(const float* __restrict__ k2t, const float* __restrict__ colmax,
                                             float* __restrict__ pinv,
                                             const float* __restrict__ ql, const u16* __restrict__ kb,
                                             const u16* __restrict__ vb,
                                             float* __restrict__ nvp, float* __restrict__ zp) {
  __shared__ __align__(16) char smem_s[81920];
  __shared__ float gsh;
  const int t = threadIdx.x;
  if (blockIdx.x < 64) {
    // ======== pinv: 6 Newton-Schulz iterations, all LDS XOR-swizzled [64][64] f32 ========
    float* aS = (float*)smem_s;        // a (normal layout)
    float* vl = aS + 4096;             // val
    float* kv = vl + 4096;
    float* t1 = kv + 4096;
    float* t2 = t1 + 4096;
    const int bh = blockIdx.x;
    const float* aT = k2t + (size_t)bh * 4096;  // aT[k][r] = a[r][k]
    if (t < 64) {
      float v = colmax[t];
      for (int off = 32; off; off >>= 1) v = fmaxf(v, __shfl_down(v, off, 64));
      if (t == 0) gsh = v;
    }
    const int row = t >> 3, c0 = (t & 7) << 3;
    // stage a into LDS: aS[r][k] = aT[k*64+r]
#pragma unroll
    for (int j = 0; j < 8; ++j) {
      const int i = t * 8 + j;
      aS[pidx(i & 63, i >> 6)] = aT[i];
    }
    __syncthreads();
    const float ginv = 1.0f / gsh;
    {
      f32x4 v0 = *(const f32x4*)(aT + row * 64 + c0);
      f32x4 v1 = *(const f32x4*)(aT + row * 64 + c0 + 4);
      v0 *= ginv; v1 *= ginv;
      *(f32x4*)&vl[pidx(row, c0)] = v0;       // val0[r][c] = aT[r][c]/g
      *(f32x4*)&vl[pidx(row, c0 + 4)] = v1;
    }
    __syncthreads();
    float acc[8];
    for (int it = 0; it < 6; ++it) {
      mm64s(aS, vl, row, c0, acc);            // kv = a @ val
#pragma unroll
      for (int j = 0; j < 8; ++j) kv[pidx(row, c0 + j)] = acc[j];
      __syncthreads();
#pragma unroll
      for (int j = 0; j < 8; ++j) {           // t1 = 7I - kv
        const int c = c0 + j;
        t1[pidx(row, c)] = ((row == c) ? 7.0f : 0.0f) - kv[pidx(row, c)];
      }
      __syncthreads();
      mm64s(kv, t1, row, c0, acc);            // t2 = 15I - kv@t1
#pragma unroll
      for (int j = 0; j < 8; ++j) {
        const int c = c0 + j;
        t2[pidx(row, c)] = ((row == c) ? 15.0f : 0.0f) - acc[j];
      }
      __syncthreads();
      mm64s(kv, t2, row, c0, acc);            // t1 = 13I - kv@t2
#pragma unroll
      for (int j = 0; j < 8; ++j) {
        const int c = c0 + j;
        t1[pidx(row, c)] = ((row == c) ? 13.0f : 0.0f) - acc[j];
      }
      __syncthreads();
      mm64s(vl, t1, row, c0, acc);            // t2 = 0.25 * val@t1
#pragma unroll
      for (int j = 0; j < 8; ++j) t2[pidx(row, c0 + j)] = 0.25f * acc[j];
      __syncthreads();
#pragma unroll
      for (int j = 0; j < 8; ++j) vl[pidx(row, c0 + j)] = t2[pidx(row, c0 + j)];  // val = t2
      __syncthreads();
    }
    {
      f32x4 o0 = *(const f32x4*)&vl[pidx(row, c0)];
      f32x4 o1 = *(const f32x4*)&vl[pidx(row, c0 + 4)];
      *(f32x4*)(pinv + (size_t)bh * 4096 + row * 64 + c0) = o0;
      *(f32x4*)(pinv + (size_t)bh * 4096 + row * 64 + c0 + 4) = o1;
    }
    return;
  }
  // ======== s3+nv: 512 threads = 2 S-halves x 4 L-quarter waves ========
  u16* VTs = (u16*)smem_s;                    // [2 buf][2 half][64][72]
  u16* els = (u16*)(smem_s + 36864);          // [8][16][72]
  const int id = (int)blockIdx.x - 64;
  const int bh = id & 63, scn = id >> 6;      // scn in [0,8)
  const int lane = t & 63, w = t >> 6;
  const int wq = w & 3, half = w >> 2;
  const int l15 = lane & 15, kg = (lane >> 4) << 3, rl = (lane >> 4) << 2;
  const float* aRow = ql + (size_t)bh * 4096 + (wq * 16 + l15) * 64 + kg;
  bf16x8 aql[2];
  aql[0] = ld_f32_to_bf8(aRow);
  aql[1] = ld_f32_to_bf8(aRow + 32);
  f32x4 accv[4];
#pragma unroll
  for (int n = 0; n < 4; ++n) accv[n] = (f32x4){0.f, 0.f, 0.f, 0.f};
  float zacc[4] = {0.f, 0.f, 0.f, 0.f};
  const int sBase = scn * 512 + half * 256;
  u16* VT0 = VTs + ((size_t)(0 * 2 + half) * 64) * 72;
  u16* VT1 = VTs + ((size_t)(1 * 2 + half) * 64) * 72;
  u16* elw = els + ((size_t)w * 16) * 72;
  // preload sub 0 into VT0
  {
    const u16* vp = vb + ((size_t)bh * 4096 + sBase + lane) * 64 + wq * 16;
    u16x8 h0 = *(const u16x8*)vp, h1 = *(const u16x8*)(vp + 8);
#pragma unroll
    for (int j = 0; j < 8; ++j) {
      VT0[(wq * 16 + j) * 72 + lane] = h0[j];
      VT0[(wq * 16 + 8 + j) * 72 + lane] = h1[j];
    }
  }
  __syncthreads();
  for (int sub = 0; sub < 4; ++sub) {
    const int s0 = sBase + sub * 64;
    u16x8 hn0 = {0, 0, 0, 0, 0, 0, 0, 0}, hn1 = {0, 0, 0, 0, 0, 0, 0, 0};
    if (sub < 3) {  // prefetch next V tile into regs
      const u16* vpn = vb + ((size_t)bh * 4096 + s0 + 64 + lane) * 64 + wq * 16;
      hn0 = *(const u16x8*)vpn; hn1 = *(const u16x8*)(vpn + 8);
    }
    const u16* bRow = kb + ((size_t)bh * 4096 + s0 + l15) * 64 + kg;
    f32x4 e[4];
#pragma unroll
    for (int n = 0; n < 4; ++n) e[n] = (f32x4){0.f, 0.f, 0.f, 0.f};
#pragma unroll
    for (int ks = 0; ks < 2; ++ks)
#pragma unroll
      for (int n = 0; n < 4; ++n) {
        bf16x8 bk_ = *reinterpret_cast<const bf16x8*>(bRow + n * 1024 + ks * 32);
        e[n] = __builtin_amdgcn_mfma_f32_16x16x32_bf16(aql[ks], bk_, e[n], 0, 0, 0);
      }
#pragma unroll
    for (int n = 0; n < 4; ++n)
#pragma unroll
      for (int r = 0; r < 4; ++r) {
        const float v = __expf(e[n][r]);
        zacc[r] += v;
        elw[(rl + r) * 72 + n * 16 + l15] = f2bf(v);
      }
    if (sub < 3) {
      u16* VTn = ((sub + 1) & 1) ? VT1 : VT0;
#pragma unroll
      for (int j = 0; j < 8; ++j) {
        VTn[(wq * 16 + j) * 72 + lane] = hn0[j];
        VTn[(wq * 16 + 8 + j) * 72 + lane] = hn1[j];
      }
    }
    WAIT_LGKM0();  // own e_lds + VT writes complete
    const u16* VTc = (sub & 1) ? VT1 : VT0;
#pragma unroll
    for (int ks = 0; ks < 2; ++ks) {
      bf16x8 af = *reinterpret_cast<const bf16x8*>(&elw[l15 * 72 + kg + ks * 32]);
#pragma unroll
      for (int n = 0; n < 4; ++n) {
        bf16x8 bf_ = *reinterpret_cast<const bf16x8*>(&VTc[(n * 16 + l15) * 72 + kg + ks * 32]);
        accv[n] = __builtin_amdgcn_mfma_f32_16x16x32_bf16(af, bf_, accv[n], 0, 0, 0);
      }
    }
    BAR();  // publish next VT buf; WAR fence on current
  }
  const int p = scn * 2 + half;
#pragma unroll
  for (int r = 0; r < 4; ++r)
#pragma unroll
    for (int n = 0; n < 4; ++n)
      nvp[(((size_t)p * 64 + bh) * 64 + wq * 16 + rl + r) * 64 + n * 16 + l15] = accv[n][r];
#pragma unroll
  for (int r = 0; r < 4; ++r) {
    float s = zacc[r];
    s += __shfl_xor(s, 1, 64); s += __shfl_xor(s, 2, 64);
    s += __shfl_xor(s, 4, 64); s += __shfl_xor(s, 8, 64);
    if (l15 == 0) zp[((size_t)p * 64 + bh) * 64 + wq * 16 + rl + r] = s;
  }
}

// ---------------- M^T (bf16) = (pinv @ (sum(nvp)/sum(zp)))^T ----------------
__global__ __launch_bounds__(256) void k_pnv(const float* __restrict__ pinv, const float* __restrict__ nvp,
                                             const float* __restrict__ zp, u16* __restrict__ Mtb) {
  __shared__ __align__(16) float XT[64 * 68];
  __shared__ __align__(16) float Y[64 * 68];
  const int bh = blockIdx.x, t = threadIdx.x;
  {
    const int r = t >> 2, c0 = (t & 3) * 16;
    const float* pp = pinv + (size_t)bh * 4096 + r * 64 + c0;
#pragma unroll
    for (int j = 0; j < 16; ++j) XT[(c0 + j) * 68 + r] = pp[j];
    float zs = 0.f;
#pragma unroll
    for (int p = 0; p < 16; ++p) zs += zp[((size_t)p * 64 + bh) * 64 + r];
    const float iz = 1.0f / zs;
#pragma unroll
    for (int j = 0; j < 16; ++j) {
      float s = 0.f;
#pragma unroll
      for (int p = 0; p < 16; ++p) s += nvp[(((size_t)p * 64 + bh) * 64 + r) * 64 + c0 + j];
      Y[r * 68 + c0 + j] = s * iz;
    }
  }
  __syncthreads();
  const int rg = (t >> 4) * 4, cg = (t & 15) * 4;
  float acc[4][4];
#pragma unroll
  for (int i = 0; i < 4; ++i)
#pragma unroll
    for (int j = 0; j < 4; ++j) acc[i][j] = 0.f;
  for (int k = 0; k < 64; ++k) {
    f32x4 x = *(const f32x4*)&XT[k * 68 + rg];
    f32x4 y = *(const f32x4*)&Y[k * 68 + cg];
#pragma unroll
    for (int i = 0; i < 4; ++i)
#pragma unroll
      for (int j = 0; j < 4; ++j) acc[i][j] += x[i] * y[j];
  }
#pragma unroll
  for (int j = 0; j < 4; ++j) {
    u16x4 o = {f2bf(acc[0][j]), f2bf(acc[1][j]), f2bf(acc[2][j]), f2bf(acc[3][j])};
    *(u16x4*)&Mtb[(size_t)bh * 4096 + (cg + j) * 64 + rg] = o;
  }
}

// ---------------- final: softmax(q·kl^T) @ M^T + depthwise conv ----------------
__global__ __launch_bounds__(256) void k_out(const u16* __restrict__ qb, const u16* __restrict__ vb,
                                             const u16* __restrict__ klb, const u16* __restrict__ Mtb,
                                             const float* __restrict__ cw, float* __restrict__ out) {
  __shared__ __align__(16) u16 P_lds[4][16][72];
  __shared__ __align__(16) u16 vtile_t[64][100];  // [d][row]
  __shared__ float wsh[33];
  const int bid = blockIdx.x;
  const int bh = bid >> 6, st = bid & 63;
  const int b = bh >> 4, h = bh & 15;
  const int t = threadIdx.x, lane = t & 63, w = t >> 6;
  const int sbase = st * 64;
  const int l15 = lane & 15, kg = (lane >> 4) << 3, rl = (lane >> 4) << 2;

  if (t < 33) wsh[t] = cw[h * 33 + t];
  for (int idx = t; idx < 96 * 8; idx += 256) {
    const int row = idx >> 3, c8 = idx & 7;
    const int sg = sbase + row - 16;
    u16x8 val = {0, 0, 0, 0, 0, 0, 0, 0};
    if (sg >= 0 && sg < 4096) val = *(const u16x8*)(vb + ((size_t)bh * 4096 + sg) * 64 + c8 * 8);
#pragma unroll
    for (int j = 0; j < 8; ++j) vtile_t[c8 * 8 + j][row] = val[j];
  }

  f32x4 c1[4];
#pragma unroll
  for (int n = 0; n < 4; ++n) c1[n] = (f32x4){0.f, 0.f, 0.f, 0.f};
  {
    const u16* aRow = qb + ((size_t)bh * 4096 + sbase + w * 16 + l15) * 64 + kg;
    const u16* kRow = klb + (size_t)bh * 4096 + l15 * 64 + kg;
#pragma unroll
    for (int ks = 0; ks < 2; ++ks) {
      bf16x8 af = *reinterpret_cast<const bf16x8*>(aRow + ks * 32);
#pragma unroll
      for (int n = 0; n < 4; ++n) {
        bf16x8 bf_ = *reinterpret_cast<const bf16x8*>(kRow + n * 1024 + ks * 32);
        c1[n] = __builtin_amdgcn_mfma_f32_16x16x32_bf16(af, bf_, c1[n], 0, 0, 0);
      }
    }
  }
  float invZ[4];
  {
    float z[4] = {0.f, 0.f, 0.f, 0.f};
#pragma unroll
    for (int n = 0; n < 4; ++n)
#pragma unroll
      for (int r = 0; r < 4; ++r) { float v = __expf(c1[n][r]); c1[n][r] = v; z[r] += v; }
#pragma unroll
    for (int r = 0; r < 4; ++r) {
      float s = z[r];
      s += __shfl_xor(s, 1, 64); s += __shfl_xor(s, 2, 64);
      s += __shfl_xor(s, 4, 64); s += __shfl_xor(s, 8, 64);
      invZ[r] = 1.0f / s;
    }
#pragma unroll
    for (int n = 0; n < 4; ++n)
#pragma unroll
      for (int r = 0; r < 4; ++r)
        P_lds[w][rl + r][n * 16 + l15] = f2bf(c1[n][r]);
  }
  __syncthreads();
  f32x4 c2[4];
#pragma unroll
  for (int n = 0; n < 4; ++n) c2[n] = (f32x4){0.f, 0.f, 0.f, 0.f};
  {
    const u16* mRow = Mtb + (size_t)bh * 4096 + l15 * 64 + kg;
#pragma unroll
    for (int ks = 0; ks < 2; ++ks) {
      bf16x8 af = *reinterpret_cast<const bf16x8*>(&P_lds[w][l15][kg + ks * 32]);
#pragma unroll
      for (int n = 0; n < 4; ++n) {
        bf16x8 bf_ = *reinterpret_cast<const bf16x8*>(mRow + n * 1024 + ks * 32);
        c2[n] = __builtin_amdgcn_mfma_f32_16x16x32_bf16(af, bf_, c2[n], 0, 0, 0);
      }
    }
  }
  const int base = w * 16 + rl;
#pragma unroll
  for (int n = 0; n < 4; ++n) {
    const int d = n * 16 + l15;
    float vcol[36];
#pragma unroll
    for (int k8 = 0; k8 < 9; ++k8) {
      u16x4 vq = *(const u16x4*)&vtile_t[d][base + k8 * 4];
      vcol[k8 * 4 + 0] = bf2f(vq[0]); vcol[k8 * 4 + 1] = bf2f(vq[1]);
      vcol[k8 * 4 + 2] = bf2f(vq[2]); vcol[k8 * 4 + 3] = bf2f(vq[3]);
    }
    float cv[4] = {0.f, 0.f, 0.f, 0.f};
#pragma unroll
    for (int jt = 0; jt < 33; ++jt) {
      const float ww = wsh[jt];
#pragma unroll
      for (int r = 0; r < 4; ++r) cv[r] += ww * vcol[r + jt];
    }
#pragma unroll
    for (int r = 0; r < 4; ++r) {
      const int sgl = sbase + base + r;
      out[((size_t)b * 4096 + sgl) * 1024 + h * 64 + d] = c2[n][r] * invZ[r] + cv[r];
    }
  }
}

extern "C" void kernel_launch(void* const* d_in, const int* in_sizes, int n_in,
                              void* d_out, int out_size, void* d_ws, size_t ws_size,
                              hipStream_t stream) {
  const float* hidden = (const float*)d_in[0];
  const float* Wq = (const float*)d_in[1];
  const float* bq = (const float*)d_in[2];
  const float* Wk = (const float*)d_in[3];
  const float* bk = (const float*)d_in[4];
  const float* Wv = (const float*)d_in[5];
  const float* bv = (const float*)d_in[6];
  const float* cw = (const float*)d_in[7];
  float* out = (float*)d_out;

  char* ws = (char*)d_ws;
  u16* qb = (u16*)(ws);                           // 32MB
  u16* kb = (u16*)(ws + 33554432ull);             // 32MB
  u16* vb = (u16*)(ws + 67108864ull);             // 32MB
  float* ql = (float*)(ws + 100663296ull);        // 1MB
  float* kl = (float*)(ws + 101711872ull);        // 1MB
  float* k2t = (float*)(ws + 102760448ull);       // 1MB
  float* pinvb = (float*)(ws + 103809024ull);     // 1MB
  u16* Mtb = (u16*)(ws + 104857600ull);           // 512KB
  u16* klb = (u16*)(ws + 105381888ull);           // 1MB
  float* stats = (float*)(ws + 106430464ull);     // 4KB
  u16* wt = (u16*)(ws + 106434560ull);            // 6MB, dead after k_gemm2
  u16* hb = (u16*)(ws + 112726016ull);            // 32MB, dead after k_gemm2
  float* nvp = (float*)(ws + 112726016ull);       // 16.8MB, aliases hb (dead)
  float* zp = (float*)(ws + 129503232ull);        // 256KB

  k_prep<<<8960, 256, 0, stream>>>(hidden, Wq, Wk, Wv, hb, wt);
  k_gemm2<<<768, 512, 0, stream>>>(hb, wt, bq, bk, bv, qb, kb, vb, ql, kl);
  k_k2<<<64, 256, 0, stream>>>(ql, kl, k2t, stats, klb);
  k_mid<<<576, 512, 0, stream>>>(k2t, stats, pinvb, ql, kb, vb, nvp, zp);
  k_pnv<<<64, 256, 0, stream>>>(pinvb, nvp, zp, Mtb);
  k_out<<<4096, 256, 0, stream>>>(qb, vb, klb, Mtb, cw, out);
  (void)in_sizes; (void)n_in; (void)out_size; (void)ws_size;
}

// Round 11
// 318.437 us; speedup vs baseline: 1.0038x; 1.0013x over previous
//
#include <hip/hip_runtime.h>
#include <stdint.h>

typedef unsigned short u16;
typedef float f32x4 __attribute__((ext_vector_type(4)));
typedef __bf16 bf16x8 __attribute__((ext_vector_type(8)));
typedef u16 u16x8 __attribute__((ext_vector_type(8)));
typedef u16 u16x4 __attribute__((ext_vector_type(4)));

#define SCALE_QK 0.35355339059327373f

#define BAR() asm volatile("s_barrier" ::: "memory")
#define WAIT_LGKM0() do { asm volatile("s_waitcnt lgkmcnt(0)" ::: "memory"); __builtin_amdgcn_sched_barrier(0); } while (0)
#define WAIT_VM(n) do { asm volatile("s_waitcnt vmcnt(" #n ")" ::: "memory"); __builtin_amdgcn_sched_barrier(0); } while (0)

__device__ __forceinline__ u16 f2bf(float f) {
  union { float f; uint32_t u; } x; x.f = f;
  uint32_t r = x.u + 0x7fffu + ((x.u >> 16) & 1u);
  return (u16)(r >> 16);
}
__device__ __forceinline__ float bf2f(u16 h) {
  union { uint32_t u; float f; } x; x.u = ((uint32_t)h) << 16;
  return x.f;
}
__device__ __forceinline__ void gload16(const void* g, void* l) {
  __builtin_amdgcn_global_load_lds((const __attribute__((address_space(1))) void*)g,
                                   (__attribute__((address_space(3))) void*)l, 16, 0, 0);
}
__device__ __forceinline__ bf16x8 ld_f32_to_bf8(const float* p) {
  f32x4 a = *(const f32x4*)p, b = *(const f32x4*)(p + 4);
  union { u16x8 u; bf16x8 h; } c;
  c.u[0] = f2bf(a[0]); c.u[1] = f2bf(a[1]); c.u[2] = f2bf(a[2]); c.u[3] = f2bf(a[3]);
  c.u[4] = f2bf(b[0]); c.u[5] = f2bf(b[1]); c.u[6] = f2bf(b[2]); c.u[7] = f2bf(b[3]);
  return c.h;
}

// ---------------- merged prep: hidden->bf16 (blocks 0..8191) + weight transpose (blocks 8192..8959) ----------------
__global__ __launch_bounds__(256) void k_prep(const float* __restrict__ hidden,
                                              const float* __restrict__ Wq, const float* __restrict__ Wk,
                                              const float* __restrict__ Wv,
                                              u16* __restrict__ hb, u16* __restrict__ Wt) {
  __shared__ float tile[64][65];
  const int bx = blockIdx.x;
  const int t = threadIdx.x;
  if (bx < 8192) {
    const size_t i = ((size_t)bx * 256 + t) * 8;
    f32x4 v0 = *(const f32x4*)(hidden + i);
    f32x4 v1 = *(const f32x4*)(hidden + i + 4);
    u16x8 o;
    o[0] = f2bf(v0[0]); o[1] = f2bf(v0[1]); o[2] = f2bf(v0[2]); o[3] = f2bf(v0[3]);
    o[4] = f2bf(v1[0]); o[5] = f2bf(v1[1]); o[6] = f2bf(v1[2]); o[7] = f2bf(v1[3]);
    *(u16x8*)(hb + i) = o;
    return;
  }
  const int bxx = bx - 8192;
  const int w = bxx >> 8, tn = (bxx >> 4) & 15, tk = bxx & 15;
  const float* W = (w == 0) ? Wq : ((w == 1) ? Wk : Wv);
  const int r = t >> 2, c0 = (t & 3) * 16;
  const float* src = W + (size_t)(tk * 64 + r) * 1024 + tn * 64 + c0;
#pragma unroll
  for (int j = 0; j < 16; j += 4) {
    f32x4 x = *(const f32x4*)(src + j);
    tile[r][c0 + j + 0] = x[0]; tile[r][c0 + j + 1] = x[1];
    tile[r][c0 + j + 2] = x[2]; tile[r][c0 + j + 3] = x[3];
  }
  __syncthreads();
  u16* dst = Wt + (size_t)(w * 1024 + tn * 64 + r) * 1024 + tk * 64 + c0;
#pragma unroll
  for (int j = 0; j < 16; ++j) dst[j] = f2bf(tile[c0 + j][r]);
}

// ---------------- 256x256x64 8-wave GEMM, counted-vmcnt pipeline + XCD-aware swizzle ----------------
__device__ __forceinline__ bf16x8 frg(const u16* buf, int row, int ks, int lhi) {
  const int ck = (ks << 2) + lhi;
  return *reinterpret_cast<const bf16x8*>(buf + (row << 6) + ((ck ^ (row & 7)) << 3));
}
__device__ __forceinline__ void issue(const u16* g, int rowbase, int tc, u16* ldsbase, int wid) {
  gload16(g + (((size_t)rowbase) << 10) + tc, ldsbase + ((rowbase + (wid << 3)) << 6));
}
template <int Q>
__device__ __forceinline__ void quad_mfma(const bf16x8 (&af)[2][2], const bf16x8 (&bf)[4][2],
                                          f32x4 (&acc)[8][4]) {
#pragma unroll
  for (int mm = 0; mm < 2; ++mm)
#pragma unroll
    for (int n = 0; n < 4; ++n) {
      acc[Q * 2 + mm][n] = __builtin_amdgcn_mfma_f32_16x16x32_bf16(af[mm][0], bf[n][0], acc[Q * 2 + mm][n], 0, 0, 0);
      acc[Q * 2 + mm][n] = __builtin_amdgcn_mfma_f32_16x16x32_bf16(af[mm][1], bf[n][1], acc[Q * 2 + mm][n], 0, 0, 0);
    }
}
#define LOADA_TO(dst, Q)                                     \
  dst[0][0] = frg(ASr, rA0 + (Q)*32, 0, lhi);                \
  dst[0][1] = frg(ASr, rA0 + (Q)*32, 1, lhi);                \
  dst[1][0] = frg(ASr, rA0 + (Q)*32 + 16, 0, lhi);           \
  dst[1][1] = frg(ASr, rA0 + (Q)*32 + 16, 1, lhi);

__global__ __launch_bounds__(512) void k_gemm2(const u16* __restrict__ A, const u16* __restrict__ Bt,
                                               const float* __restrict__ bq, const float* __restrict__ bk,
                                               const float* __restrict__ bv,
                                               u16* __restrict__ oq, u16* __restrict__ ok, u16* __restrict__ ov,
                                               float* __restrict__ ql, float* __restrict__ kl) {
  __shared__ __align__(16) u16 AS[2][256 * 64];
  __shared__ __align__(16) u16 BS[2][256 * 64];
  __shared__ __align__(16) u16 obuf[8][16][70];
  const int t = threadIdx.x, lane = t & 63, wid = t >> 6;
  const int wm = wid >> 2, wn = wid & 3;
  // XCD-aware swizzle (T1): xcd = id&7 owns bm range [8*xcd, 8*xcd+8), bn varies fastest
  // -> A-tile (0.5MB) reused 12x from the XCD's private L2 instead of L3.
  const int bi = blockIdx.x;
  const int bm = ((bi & 7) << 3) + (bi >> 3) / 12;
  const int bn = (bi >> 3) % 12;
  const int l15 = lane & 15, lhi = lane >> 4;

  const int rowoff = t >> 3;
  const int cswz = (t & 7) ^ (rowoff & 7);
  const u16* aG = A + (((size_t)(bm * 256 + rowoff)) << 10) + (cswz << 3);
  const u16* bG = Bt + (((size_t)(bn * 256 + rowoff)) << 10) + (cswz << 3);

  const int rA0 = wm * 128 + l15;
  const int rB0 = wn * 64 + l15;

  f32x4 acc[8][4];
#pragma unroll
  for (int m = 0; m < 8; ++m)
#pragma unroll
    for (int n = 0; n < 4; ++n) acc[m][n] = (f32x4){0.f, 0.f, 0.f, 0.f};

  // prologue: tile 0 -> buf 0. Order: B x4, A-q01 x2, A-q23 x2.
  issue(bG, 0, 0, BS[0], wid);
  issue(bG, 64, 0, BS[0], wid);
  issue(bG, 128, 0, BS[0], wid);
  issue(bG, 192, 0, BS[0], wid);
  issue(aG, 0, 0, AS[0], wid);
  issue(aG, 128, 0, AS[0], wid);
  issue(aG, 64, 0, AS[0], wid);
  issue(aG, 192, 0, AS[0], wid);
  WAIT_VM(2);  // B + A-q01 landed; A-q23 in flight
  BAR();

  for (int u = 0; u < 15; ++u) {
    const int pu = u & 1;
    const u16* ASr = AS[pu];
    const u16* BSr = BS[pu];
    u16* ASw = AS[pu ^ 1];
    u16* BSw = BS[pu ^ 1];
    const int tc = (u + 1) << 6;
    bf16x8 bfr[4][2];
    bf16x8 afA[2][2], afB[2][2];
    // P0: read B(8) + A-q0 + A-q1; issue ALL 8 next-tile loads; MFMA q0
#pragma unroll
    for (int n = 0; n < 4; ++n) {
      bfr[n][0] = frg(BSr, rB0 + n * 16, 0, lhi);
      bfr[n][1] = frg(BSr, rB0 + n * 16, 1, lhi);
    }
    LOADA_TO(afA, 0)
    LOADA_TO(afB, 1)
    issue(bG, 0, tc, BSw, wid);
    issue(bG, 64, tc, BSw, wid);
    issue(bG, 128, tc, BSw, wid);
    issue(bG, 192, tc, BSw, wid);
    issue(aG, 0, tc, ASw, wid);
    issue(aG, 128, tc, ASw, wid);
    issue(aG, 64, tc, ASw, wid);
    issue(aG, 192, tc, ASw, wid);
    __builtin_amdgcn_s_setprio(1);
    quad_mfma<0>(afA, bfr, acc);
    __builtin_amdgcn_s_setprio(0);
    WAIT_VM(8);  // cur-tile A-q23 landed (8 next-tile loads remain in flight)
    BAR();
    // P1: read A-q2; MFMA q1
    LOADA_TO(afA, 2)
    __builtin_amdgcn_s_setprio(1);
    quad_mfma<1>(afB, bfr, acc);
    __builtin_amdgcn_s_setprio(0);
    // P2: read A-q3; MFMA q2
    LOADA_TO(afB, 3)
    __builtin_amdgcn_s_setprio(1);
    quad_mfma<2>(afA, bfr, acc);
    __builtin_amdgcn_s_setprio(0);
    // P3: MFMA q3
    __builtin_amdgcn_s_setprio(1);
    quad_mfma<3>(afB, bfr, acc);
    __builtin_amdgcn_s_setprio(0);
    WAIT_VM(2);  // next-tile B + A-q01 landed; A-q23 stays in flight
    BAR();       // tile boundary
  }
  // peeled tile 15 (buf 1; 2 loads of its A-q23 still in flight at entry)
  {
    const u16* ASr = AS[1];
    const u16* BSr = BS[1];
    bf16x8 bfr[4][2];
    bf16x8 afA[2][2], afB[2][2];
#pragma unroll
    for (int n = 0; n < 4; ++n) {
      bfr[n][0] = frg(BSr, rB0 + n * 16, 0, lhi);
      bfr[n][1] = frg(BSr, rB0 + n * 16, 1, lhi);
    }
    LOADA_TO(afA, 0)
    LOADA_TO(afB, 1)
    quad_mfma<0>(afA, bfr, acc);
    WAIT_VM(0);
    BAR();
    LOADA_TO(afA, 2)
    quad_mfma<1>(afB, bfr, acc);
    LOADA_TO(afB, 3)
    quad_mfma<2>(afA, bfr, acc);
    quad_mfma<3>(afB, bfr, acc);
  }

  // ---- epilogue: bias+scale, LDS bounce, coalesced stores; fused landmark means ----
  const int which = bn >> 2;
  const float* bias = (which == 0) ? bq : ((which == 1) ? bk : bv);
  u16* op = (which == 0) ? oq : ((which == 1) ? ok : ov);
  const float scl = (which < 2) ? SCALE_QK : 1.0f;
  const int h = ((bn & 3) << 2) + wn;  // wave's single head
  const int rowBase2 = (bm << 8) + (wm << 7);
  const int rl = lhi << 2;
  const int srow = lane >> 2, d0 = (lane & 3) * 16;
  float bb[4];
#pragma unroll
  for (int n = 0; n < 4; ++n) bb[n] = bias[((bn & 3) << 8) + (wn << 6) + n * 16 + l15];
#pragma unroll
  for (int m = 0; m < 8; ++m) {
#pragma unroll
    for (int n = 0; n < 4; ++n)
#pragma unroll
      for (int r = 0; r < 4; ++r)
        obuf[wid][rl + r][n * 16 + l15] = f2bf((acc[m][n][r] + bb[n]) * scl);
    const int gm = rowBase2 + m * 16 + srow;
    const int b_ = gm >> 12, s = gm & 4095;
    u16* dst = op + (((size_t)b_ * 16 + h) * 4096 + s) * 64 + d0;
    *(u16x8*)dst = *(const u16x8*)&obuf[wid][srow][d0];
    *(u16x8*)(dst + 8) = *(const u16x8*)&obuf[wid][srow][d0 + 8];
  }
  // landmark segment means (q/k only)
  if (which < 2) {
    float* lmp = (which == 0) ? ql : kl;
    const int bh = ((bm >> 4) << 4) + h;
#pragma unroll
    for (int sg = 0; sg < 2; ++sg) {
#pragma unroll
      for (int n = 0; n < 4; ++n) {
        float s = 0.f;
#pragma unroll
        for (int mi = 0; mi < 4; ++mi)
#pragma unroll
          for (int r = 0; r < 4; ++r) s += (acc[sg * 4 + mi][n][r] + bb[n]) * scl;
        s += __shfl_xor(s, 16, 64);
        s += __shfl_xor(s, 32, 64);
        if (lhi == 0) {
          const int lseg = ((bm & 15) << 2) + (wm << 1) + sg;
          lmp[(size_t)bh * 4096 + lseg * 64 + n * 16 + l15] = s * 0.015625f;
        }
      }
    }
  }
}

// ---------------- kernel_2 = softmax(ql@kl^T); k2t + colmax; also emit klb bf16 ----------------
__global__ __launch_bounds__(256) void k_k2(const float* __restrict__ ql, const float* __restrict__ kl,
                                            float* __restrict__ k2t, float* __restrict__ colmax,
                                            u16* __restrict__ klb) {
  __shared__ __align__(16) float qlT[64 * 68];
  __shared__ __align__(16) float klT[64 * 68];
  __shared__ __align__(16) float sc[64 * 68];
  const int bh = blockIdx.x, t = threadIdx.x;
  {
    const int r = t >> 2, c0 = (t & 3) * 16;
    const float* qp = ql + (size_t)bh * 4096 + r * 64 + c0;
    const float* kp = kl + (size_t)bh * 4096 + r * 64 + c0;
    u16* kb_ = klb + (size_t)bh * 4096 + r * 64 + c0;
#pragma unroll
    for (int j = 0; j < 16; ++j) {
      qlT[(c0 + j) * 68 + r] = qp[j];
      const float kv = kp[j];
      klT[(c0 + j) * 68 + r] = kv;
      kb_[j] = f2bf(kv);
    }
  }
  __syncthreads();
  {
    const int mg = (t >> 4) * 4, lg = (t & 15) * 4;
    float acc[4][4];
#pragma unroll
    for (int i = 0; i < 4; ++i)
#pragma unroll
      for (int j = 0; j < 4; ++j) acc[i][j] = 0.f;
    for (int d0 = 0; d0 < 64; ++d0) {
      f32x4 x = *(const f32x4*)&qlT[d0 * 68 + mg];
      f32x4 y = *(const f32x4*)&klT[d0 * 68 + lg];
#pragma unroll
      for (int i = 0; i < 4; ++i)
#pragma unroll
        for (int j = 0; j < 4; ++j) acc[i][j] += x[i] * y[j];
    }
#pragma unroll
    for (int i = 0; i < 4; ++i)
#pragma unroll
      for (int j = 0; j < 4; ++j) sc[(mg + i) * 68 + lg + j] = acc[i][j];
  }
  __syncthreads();
  if (t < 64) {
    float mx = -1e30f;
    for (int l = 0; l < 64; ++l) mx = fmaxf(mx, sc[t * 68 + l]);
    float sum = 0.f;
    for (int l = 0; l < 64; ++l) { float e = __expf(sc[t * 68 + l] - mx); sc[t * 68 + l] = e; sum += e; }
    const float inv = 1.0f / sum;
    for (int l = 0; l < 64; ++l) sc[t * 68 + l] *= inv;
  }
  __syncthreads();
  {
    const int r = t >> 2, c0 = (t & 3) * 16;
    float* ot = k2t + (size_t)bh * 4096 + r * 64 + c0;
#pragma unroll
    for (int j = 0; j < 16; ++j) ot[j] = sc[(c0 + j) * 68 + r];
  }
  if (t < 64) {
    float s = 0.f;
    for (int m = 0; m < 64; ++m) s += sc[m * 68 + t];
    for (int off = 32; off; off >>= 1) s = fmaxf(s, __shfl_down(s, off, 64));
    if (t == 0) colmax[bh] = s;
  }
}

// ---------------- merged mid: blocks 0..63 = pinv (XOR-swizzled LDS), 64..575 = s3+nv ----------------
__device__ __forceinline__ int pidx(int row, int c) {
  return (row << 6) + ((((c >> 2) ^ (row & 15)) << 2) | (c & 3));
}
__device__ __forceinline__ void mm64s(const float* __restrict__ X, const float* __restrict__ Y,
                                      int row, int c0, float* __restrict__ acc) {
#pragma unroll
  for (int j = 0; j < 8; ++j) acc[j] = 0.f;
  for (int kc = 0; kc < 16; ++kc) {
    f32x4 xq = *(const f32x4*)&X[pidx(row, kc << 2)];
#pragma unroll
    for (int kk = 0; kk < 4; ++kk) {
      const int k = (kc << 2) + kk;
      f32x4 y0 = *(const f32x4*)&Y[pidx(k, c0)];
      f32x4 y1 = *(const f32x4*)&Y[pidx(k, c0 + 4)];
      const float x = xq[kk];
#pragma unroll
      for (int j = 0; j < 4; ++j) { acc[j] += x * y0[j]; acc[4 + j] += x * y1[j]; }
    }
  }
}

__global__ __launch_bounds__(512) void k_mid(const float* __restrict__ k2t, const float* __restrict__ colmax,
                                             float* __restrict__ pinv,
                                             const float* __restrict__ ql, const u16* __restrict__ kb,
                                             const u16* __restrict__ vb,
                                             float* __restrict__ nvp, float* __restrict__ zp) {
  __shared__ __align__(16) char smem_s[81920];
  __shared__ float gsh;
  const int t = threadIdx.x;
  if (blockIdx.x < 64) {
    // ======== pinv: 6 Newton-Schulz iterations, all LDS XOR-swizzled [64][64] f32 ========
    float* aS = (float*)smem_s;        // a (normal layout)
    float* vl = aS + 4096;             // val
    float* kv = vl + 4096;
    float* t1 = kv + 4096;
    float* t2 = t1 + 4096;
    const int bh = blockIdx.x;
    const float* aT = k2t + (size_t)bh * 4096;  // aT[k][r] = a[r][k]
    if (t < 64) {
      float v = colmax[t];
      for (int off = 32; off; off >>= 1) v = fmaxf(v, __shfl_down(v, off, 64));
      if (t == 0) gsh = v;
    }
    const int row = t >> 3, c0 = (t & 7) << 3;
    // stage a into LDS: aS[r][k] = aT[k*64+r]
#pragma unroll
    for (int j = 0; j < 8; ++j) {
      const int i = t * 8 + j;
      aS[pidx(i & 63, i >> 6)] = aT[i];
    }
    __syncthreads();
    const float ginv = 1.0f / gsh;
    {
      f32x4 v0 = *(const f32x4*)(aT + row * 64 + c0);
      f32x4 v1 = *(const f32x4*)(aT + row * 64 + c0 + 4);
      v0 *= ginv; v1 *= ginv;
      *(f32x4*)&vl[pidx(row, c0)] = v0;       // val0[r][c] = aT[r][c]/g
      *(f32x4*)&vl[pidx(row, c0 + 4)] = v1;
    }
    __syncthreads();
    float acc[8];
    for (int it = 0; it < 6; ++it) {
      mm64s(aS, vl, row, c0, acc);            // kv = a @ val
#pragma unroll
      for (int j = 0; j < 8; ++j) kv[pidx(row, c0 + j)] = acc[j];
      __syncthreads();
#pragma unroll
      for (int j = 0; j < 8; ++j) {           // t1 = 7I - kv
        const int c = c0 + j;
        t1[pidx(row, c)] = ((row == c) ? 7.0f : 0.0f) - kv[pidx(row, c)];
      }
      __syncthreads();
      mm64s(kv, t1, row, c0, acc);            // t2 = 15I - kv@t1
#pragma unroll
      for (int j = 0; j < 8; ++j) {
        const int c = c0 + j;
        t2[pidx(row, c)] = ((row == c) ? 15.0f : 0.0f) - acc[j];
      }
      __syncthreads();
      mm64s(kv, t2, row, c0, acc);            // t1 = 13I - kv@t2
#pragma unroll
      for (int j = 0; j < 8; ++j) {
        const int c = c0 + j;
        t1[pidx(row, c)] = ((row == c) ? 13.0f : 0.0f) - acc[j];
      }
      __syncthreads();
      mm64s(vl, t1, row, c0, acc);            // t2 = 0.25 * val@t1
#pragma unroll
      for (int j = 0; j < 8; ++j) t2[pidx(row, c0 + j)] = 0.25f * acc[j];
      __syncthreads();
#pragma unroll
      for (int j = 0; j < 8; ++j) vl[pidx(row, c0 + j)] = t2[pidx(row, c0 + j)];  // val = t2
      __syncthreads();
    }
    {
      f32x4 o0 = *(const f32x4*)&vl[pidx(row, c0)];
      f32x4 o1 = *(const f32x4*)&vl[pidx(row, c0 + 4)];
      *(f32x4*)(pinv + (size_t)bh * 4096 + row * 64 + c0) = o0;
      *(f32x4*)(pinv + (size_t)bh * 4096 + row * 64 + c0 + 4) = o1;
    }
    return;
  }
  // ======== s3+nv: 512 threads = 2 S-halves x 4 L-quarter waves ========
  u16* VTs = (u16*)smem_s;                    // [2 buf][2 half][64][72]
  u16* els = (u16*)(smem_s + 36864);          // [8][16][72]
  const int id = (int)blockIdx.x - 64;
  const int bh = id & 63, scn = id >> 6;      // scn in [0,8)
  const int lane = t & 63, w = t >> 6;
  const int wq = w & 3, half = w >> 2;
  const int l15 = lane & 15, kg = (lane >> 4) << 3, rl = (lane >> 4) << 2;
  const float* aRow = ql + (size_t)bh * 4096 + (wq * 16 + l15) * 64 + kg;
  bf16x8 aql[2];
  aql[0] = ld_f32_to_bf8(aRow);
  aql[1] = ld_f32_to_bf8(aRow + 32);
  f32x4 accv[4];
#pragma unroll
  for (int n = 0; n < 4; ++n) accv[n] = (f32x4){0.f, 0.f, 0.f, 0.f};
  float zacc[4] = {0.f, 0.f, 0.f, 0.f};
  const int sBase = scn * 512 + half * 256;
  u16* VT0 = VTs + ((size_t)(0 * 2 + half) * 64) * 72;
  u16* VT1 = VTs + ((size_t)(1 * 2 + half) * 64) * 72;
  u16* elw = els + ((size_t)w * 16) * 72;
  // preload sub 0 into VT0
  {
    const u16* vp = vb + ((size_t)bh * 4096 + sBase + lane) * 64 + wq * 16;
    u16x8 h0 = *(const u16x8*)vp, h1 = *(const u16x8*)(vp + 8);
#pragma unroll
    for (int j = 0; j < 8; ++j) {
      VT0[(wq * 16 + j) * 72 + lane] = h0[j];
      VT0[(wq * 16 + 8 + j) * 72 + lane] = h1[j];
    }
  }
  __syncthreads();
  for (int sub = 0; sub < 4; ++sub) {
    const int s0 = sBase + sub * 64;
    u16x8 hn0 = {0, 0, 0, 0, 0, 0, 0, 0}, hn1 = {0, 0, 0, 0, 0, 0, 0, 0};
    if (sub < 3) {  // prefetch next V tile into regs
      const u16* vpn = vb + ((size_t)bh * 4096 + s0 + 64 + lane) * 64 + wq * 16;
      hn0 = *(const u16x8*)vpn; hn1 = *(const u16x8*)(vpn + 8);
    }
    const u16* bRow = kb + ((size_t)bh * 4096 + s0 + l15) * 64 + kg;
    f32x4 e[4];
#pragma unroll
    for (int n = 0; n < 4; ++n) e[n] = (f32x4){0.f, 0.f, 0.f, 0.f};
#pragma unroll
    for (int ks = 0; ks < 2; ++ks)
#pragma unroll
      for (int n = 0; n < 4; ++n) {
        bf16x8 bk_ = *reinterpret_cast<const bf16x8*>(bRow + n * 1024 + ks * 32);
        e[n] = __builtin_amdgcn_mfma_f32_16x16x32_bf16(aql[ks], bk_, e[n], 0, 0, 0);
      }
#pragma unroll
    for (int n = 0; n < 4; ++n)
#pragma unroll
      for (int r = 0; r < 4; ++r) {
        const float v = __expf(e[n][r]);
        zacc[r] += v;
        elw[(rl + r) * 72 + n * 16 + l15] = f2bf(v);
      }
    if (sub < 3) {
      u16* VTn = ((sub + 1) & 1) ? VT1 : VT0;
#pragma unroll
      for (int j = 0; j < 8; ++j) {
        VTn[(wq * 16 + j) * 72 + lane] = hn0[j];
        VTn[(wq * 16 + 8 + j) * 72 + lane] = hn1[j];
      }
    }
    WAIT_LGKM0();  // own e_lds + VT writes complete
    const u16* VTc = (sub & 1) ? VT1 : VT0;
#pragma unroll
    for (int ks = 0; ks < 2; ++ks) {
      bf16x8 af = *reinterpret_cast<const bf16x8*>(&elw[l15 * 72 + kg + ks * 32]);
#pragma unroll
      for (int n = 0; n < 4; ++n) {
        bf16x8 bf_ = *reinterpret_cast<const bf16x8*>(&VTc[(n * 16 + l15) * 72 + kg + ks * 32]);
        accv[n] = __builtin_amdgcn_mfma_f32_16x16x32_bf16(af, bf_, accv[n], 0, 0, 0);
      }
    }
    BAR();  // publish next VT buf; WAR fence on current
  }
  const int p = scn * 2 + half;
#pragma unroll
  for (int r = 0; r < 4; ++r)
#pragma unroll
    for (int n = 0; n < 4; ++n)
      nvp[(((size_t)p * 64 + bh) * 64 + wq * 16 + rl + r) * 64 + n * 16 + l15] = accv[n][r];
#pragma unroll
  for (int r = 0; r < 4; ++r) {
    float s = zacc[r];
    s += __shfl_xor(s, 1, 64); s += __shfl_xor(s, 2, 64);
    s += __shfl_xor(s, 4, 64); s += __shfl_xor(s, 8, 64);
    if (l15 == 0) zp[((size_t)p * 64 + bh) * 64 + wq * 16 + rl + r] = s;
  }
}

// ---------------- M^T (bf16) = (pinv @ (sum(nvp)/sum(zp)))^T ----------------
__global__ __launch_bounds__(256) void k_pnv(const float* __restrict__ pinv, const float* __restrict__ nvp,
                                             const float* __restrict__ zp, u16* __restrict__ Mtb) {
  __shared__ __align__(16) float XT[64 * 68];
  __shared__ __align__(16) float Y[64 * 68];
  const int bh = blockIdx.x, t = threadIdx.x;
  {
    const int r = t >> 2, c0 = (t & 3) * 16;
    const float* pp = pinv + (size_t)bh * 4096 + r * 64 + c0;
#pragma unroll
    for (int j = 0; j < 16; ++j) XT[(c0 + j) * 68 + r] = pp[j];
    float zs = 0.f;
#pragma unroll
    for (int p = 0; p < 16; ++p) zs += zp[((size_t)p * 64 + bh) * 64 + r];
    const float iz = 1.0f / zs;
#pragma unroll
    for (int j = 0; j < 16; ++j) {
      float s = 0.f;
#pragma unroll
      for (int p = 0; p < 16; ++p) s += nvp[(((size_t)p * 64 + bh) * 64 + r) * 64 + c0 + j];
      Y[r * 68 + c0 + j] = s * iz;
    }
  }
  __syncthreads();
  const int rg = (t >> 4) * 4, cg = (t & 15) * 4;
  float acc[4][4];
#pragma unroll
  for (int i = 0; i < 4; ++i)
#pragma unroll
    for (int j = 0; j < 4; ++j) acc[i][j] = 0.f;
  for (int k = 0; k < 64; ++k) {
    f32x4 x = *(const f32x4*)&XT[k * 68 + rg];
    f32x4 y = *(const f32x4*)&Y[k * 68 + cg];
#pragma unroll
    for (int i = 0; i < 4; ++i)
#pragma unroll
      for (int j = 0; j < 4; ++j) acc[i][j] += x[i] * y[j];
  }
#pragma unroll
  for (int j = 0; j < 4; ++j) {
    u16x4 o = {f2bf(acc[0][j]), f2bf(acc[1][j]), f2bf(acc[2][j]), f2bf(acc[3][j])};
    *(u16x4*)&Mtb[(size_t)bh * 4096 + (cg + j) * 64 + rg] = o;
  }
}

// ---------------- final: softmax(q·kl^T) @ M^T + depthwise conv ----------------
__global__ __launch_bounds__(256) void k_out(const u16* __restrict__ qb, const u16* __restrict__ vb,
                                             const u16* __restrict__ klb, const u16* __restrict__ Mtb,
                                             const float* __restrict__ cw, float* __restrict__ out) {
  __shared__ __align__(16) u16 P_lds[4][16][72];
  __shared__ __align__(16) u16 vtile_t[64][100];  // [d][row]
  __shared__ float wsh[33];
  const int bid = blockIdx.x;
  const int bh = bid >> 6, st = bid & 63;
  const int b = bh >> 4, h = bh & 15;
  const int t = threadIdx.x, lane = t & 63, w = t >> 6;
  const int sbase = st * 64;
  const int l15 = lane & 15, kg = (lane >> 4) << 3, rl = (lane >> 4) << 2;

  if (t < 33) wsh[t] = cw[h * 33 + t];
  for (int idx = t; idx < 96 * 8; idx += 256) {
    const int row = idx >> 3, c8 = idx & 7;
    const int sg = sbase + row - 16;
    u16x8 val = {0, 0, 0, 0, 0, 0, 0, 0};
    if (sg >= 0 && sg < 4096) val = *(const u16x8*)(vb + ((size_t)bh * 4096 + sg) * 64 + c8 * 8);
#pragma unroll
    for (int j = 0; j < 8; ++j) vtile_t[c8 * 8 + j][row] = val[j];
  }

  f32x4 c1[4];
#pragma unroll
  for (int n = 0; n < 4; ++n) c1[n] = (f32x4){0.f, 0.f, 0.f, 0.f};
  {
    const u16* aRow = qb + ((size_t)bh * 4096 + sbase + w * 16 + l15) * 64 + kg;
    const u16* kRow = klb + (size_t)bh * 4096 + l15 * 64 + kg;
#pragma unroll
    for (int ks = 0; ks < 2; ++ks) {
      bf16x8 af = *reinterpret_cast<const bf16x8*>(aRow + ks * 32);
#pragma unroll
      for (int n = 0; n < 4; ++n) {
        bf16x8 bf_ = *reinterpret_cast<const bf16x8*>(kRow + n * 1024 + ks * 32);
        c1[n] = __builtin_amdgcn_mfma_f32_16x16x32_bf16(af, bf_, c1[n], 0, 0, 0);
      }
    }
  }
  float invZ[4];
  {
    float z[4] = {0.f, 0.f, 0.f, 0.f};
#pragma unroll
    for (int n = 0; n < 4; ++n)
#pragma unroll
      for (int r = 0; r < 4; ++r) { float v = __expf(c1[n][r]); c1[n][r] = v; z[r] += v; }
#pragma unroll
    for (int r = 0; r < 4; ++r) {
      float s = z[r];
      s += __shfl_xor(s, 1, 64); s += __shfl_xor(s, 2, 64);
      s += __shfl_xor(s, 4, 64); s += __shfl_xor(s, 8, 64);
      invZ[r] = 1.0f / s;
    }
#pragma unroll
    for (int n = 0; n < 4; ++n)
#pragma unroll
      for (int r = 0; r < 4; ++r)
        P_lds[w][rl + r][n * 16 + l15] = f2bf(c1[n][r]);
  }
  __syncthreads();
  f32x4 c2[4];
#pragma unroll
  for (int n = 0; n < 4; ++n) c2[n] = (f32x4){0.f, 0.f, 0.f, 0.f};
  {
    const u16* mRow = Mtb + (size_t)bh * 4096 + l15 * 64 + kg;
#pragma unroll
    for (int ks = 0; ks < 2; ++ks) {
      bf16x8 af = *reinterpret_cast<const bf16x8*>(&P_lds[w][l15][kg + ks * 32]);
#pragma unroll
      for (int n = 0; n < 4; ++n) {
        bf16x8 bf_ = *reinterpret_cast<const bf16x8*>(mRow + n * 1024 + ks * 32);
        c2[n] = __builtin_amdgcn_mfma_f32_16x16x32_bf16(af, bf_, c2[n], 0, 0, 0);
      }
    }
  }
  const int base = w * 16 + rl;
#pragma unroll
  for (int n = 0; n < 4; ++n) {
    const int d = n * 16 + l15;
    float vcol[36];
#pragma unroll
    for (int k8 = 0; k8 < 9; ++k8) {
      u16x4 vq = *(const u16x4*)&vtile_t[d][base + k8 * 4];
      vcol[k8 * 4 + 0] = bf2f(vq[0]); vcol[k8 * 4 + 1] = bf2f(vq[1]);
      vcol[k8 * 4 + 2] = bf2f(vq[2]); vcol[k8 * 4 + 3] = bf2f(vq[3]);
    }
    float cv[4] = {0.f, 0.f, 0.f, 0.f};
#pragma unroll
    for (int jt = 0; jt < 33; ++jt) {
      const float ww = wsh[jt];
#pragma unroll
      for (int r = 0; r < 4; ++r) cv[r] += ww * vcol[r + jt];
    }
#pragma unroll
    for (int r = 0; r < 4; ++r) {
      const int sgl = sbase + base + r;
      out[((size_t)b * 4096 + sgl) * 1024 + h * 64 + d] = c2[n][r] * invZ[r] + cv[r];
    }
  }
}

extern "C" void kernel_launch(void* const* d_in, const int* in_sizes, int n_in,
                              void* d_out, int out_size, void* d_ws, size_t ws_size,
                              hipStream_t stream) {
  const float* hidden = (const float*)d_in[0];
  const float* Wq = (const float*)d_in[1];
  const float* bq = (const float*)d_in[2];
  const float* Wk = (const float*)d_in[3];
  const float* bk = (const float*)d_in[4];
  const float* Wv = (const float*)d_in[5];
  const float* bv = (const float*)d_in[6];
  const float* cw = (const float*)d_in[7];
  float* out = (float*)d_out;

  char* ws = (char*)d_ws;
  u16* qb = (u16*)(ws);                           // 32MB
  u16* kb = (u16*)(ws + 33554432ull);             // 32MB
  u16* vb = (u16*)(ws + 67108864ull);             // 32MB
  float* ql = (float*)(ws + 100663296ull);        // 1MB
  float* kl = (float*)(ws + 101711872ull);        // 1MB
  float* k2t = (float*)(ws + 102760448ull);       // 1MB
  float* pinvb = (float*)(ws + 103809024ull);     // 1MB
  u16* Mtb = (u16*)(ws + 104857600ull);           // 512KB
  u16* klb = (u16*)(ws + 105381888ull);           // 1MB
  float* stats = (float*)(ws + 106430464ull);     // 4KB
  u16* wt = (u16*)(ws + 106434560ull);            // 6MB, dead after k_gemm2
  u16* hb = (u16*)(ws + 112726016ull);            // 32MB, dead after k_gemm2
  float* nvp = (float*)(ws + 112726016ull);       // 16.8MB, aliases hb (dead)
  float* zp = (float*)(ws + 129503232ull);        // 256KB

  k_prep<<<8960, 256, 0, stream>>>(hidden, Wq, Wk, Wv, hb, wt);
  k_gemm2<<<768, 512, 0, stream>>>(hb, wt, bq, bk, bv, qb, kb, vb, ql, kl);
  k_k2<<<64, 256, 0, stream>>>(ql, kl, k2t, stats, klb);
  k_mid<<<576, 512, 0, stream>>>(k2t, stats, pinvb, ql, kb, vb, nvp, zp);
  k_pnv<<<64, 256, 0, stream>>>(pinvb, nvp, zp, Mtb);
  k_out<<<4096, 256, 0, stream>>>(qb, vb, klb, Mtb, cw, out);
  (void)in_sizes; (void)n_in; (void)out_size; (void)ws_size;
}